// Round 1
// baseline (8108.771 us; speedup 1.0000x reference)
//
#include <hip/hip_runtime.h>
#include <hip/hip_fp16.h>

#define NBLK 512
#define NTHR 256

constexpr int BSZ = 32;
constexpr int TSEQ = 64;
constexpr int HID = 1024;
constexpr int EMB = 512;
constexpr int MOU = 512;     // M
constexpr int VOC = 32000;
constexpr int KX  = 2560;    // 2H + E   (x = [yi_emb, context])
constexpr int KMO = 3584;    // 3H + E   (mo_in = [si, context, yi_emb])
constexpr int G3  = 3072;    // 3H
constexpr int FC_TILES = VOC / 32;   // 1000
constexpr size_t ALPHA_OFF = (size_t)BSZ * TSEQ * VOC;
constexpr size_t BAR_BYTES = 33280;   // rel line + 512 flag lines

constexpr size_t S_Wa  = (size_t)HID * HID;
constexpr size_t S_Whh = (size_t)G3 * HID;
constexpr size_t S_Wih = (size_t)G3 * KX;
constexpr size_t S_emb = (size_t)EMB * HID;
constexpr size_t S_Ua  = (size_t)HID * 2 * HID;
constexpr size_t S_mo  = (size_t)2 * MOU * KMO;
constexpr size_t S_fc  = (size_t)VOC * MOU;
constexpr size_t S_enc = (size_t)BSZ * TSEQ * 2 * HID;

typedef _Float16 h8 __attribute__((ext_vector_type(8)));
typedef _Float16 h4v __attribute__((ext_vector_type(4)));
typedef float f4 __attribute__((ext_vector_type(4)));

__device__ inline float fast_tanh(float x) {
  float e = __expf(2.f * x);
  return (e - 1.f) / (e + 1.f);
}
__device__ inline float fast_sig(float x) { return 1.f / (1.f + __expf(-x)); }

// ---- distributed flag barrier ----
// rel = ws[0] (own line); flags[i] at ws+256 + 64*i (one line per block).
// Arrival: store g+1 to own flag (parallel, no RMW contention).
// Block 0 wave 0 polls all flags (agent-scope loads go to the coherence
// point, so no stale-L2 spin), then store-releases rel = g+1.
__device__ inline void gbar(unsigned* rel, unsigned* flags, unsigned g) {
  __syncthreads();
  if (blockIdx.x == 0) {
    if (threadIdx.x < 64) {
      __threadfence();
      const int lane = threadIdx.x;
      const int nb = gridDim.x;
      for (;;) {
        bool ok = true;
        for (int i = lane; i < nb; i += 64)
          if (i != 0)
            ok &= (__hip_atomic_load(flags + (size_t)i * 16, __ATOMIC_RELAXED,
                                     __HIP_MEMORY_SCOPE_AGENT) > g);
        if (__builtin_amdgcn_ballot_w64(ok) == ~0ull) break;
        __builtin_amdgcn_s_sleep(2);
      }
      __threadfence();
      if (lane == 0)
        __hip_atomic_store(rel, g + 1, __ATOMIC_RELAXED, __HIP_MEMORY_SCOPE_AGENT);
    }
    __syncthreads();
  } else {
    if (threadIdx.x == 0) {
      __threadfence();
      __hip_atomic_store(flags + (size_t)blockIdx.x * 16, g + 1, __ATOMIC_RELAXED,
                         __HIP_MEMORY_SCOPE_AGENT);
      while (__hip_atomic_load(rel, __ATOMIC_RELAXED, __HIP_MEMORY_SCOPE_AGENT) <= g)
        __builtin_amdgcn_s_sleep(2);
      __threadfence();
    }
    __syncthreads();
  }
}

// ---- pipelined 16x16 tile GEMM: C += A[16,klen] * W[16,klen]^T ----
template <int PF>
__device__ inline f4 gemm16p(const _Float16* A, int lda, const _Float16* W, int ldw,
                             int klen, f4 accin) {
  const int lane = threadIdx.x & 63;
  const _Float16* ap = A + (size_t)(lane & 15) * lda + ((lane >> 4) << 3);
  const _Float16* wp = W + (size_t)(lane & 15) * ldw + ((lane >> 4) << 3);
  const int nk = klen >> 5;
  f4 acc[4];
  acc[0] = accin;
  acc[1] = f4{0.f, 0.f, 0.f, 0.f};
  acc[2] = f4{0.f, 0.f, 0.f, 0.f};
  acc[3] = f4{0.f, 0.f, 0.f, 0.f};
  h8 ab[PF], wb[PF];
#pragma unroll
  for (int i = 0; i < PF; i++) {
    ab[i] = *(const h8*)(ap + 32 * i);
    wb[i] = *(const h8*)(wp + 32 * i);
  }
  for (int kb = PF; kb < nk; kb += PF) {
#pragma unroll
    for (int i = 0; i < PF; i++) {
      h8 a = ab[i], w = wb[i];
      ab[i] = *(const h8*)(ap + 32 * (kb + i));
      wb[i] = *(const h8*)(wp + 32 * (kb + i));
      acc[i & 3] = __builtin_amdgcn_mfma_f32_16x16x32_f16(a, w, acc[i & 3], 0, 0, 0);
    }
  }
#pragma unroll
  for (int i = 0; i < PF; i++)
    acc[i & 3] = __builtin_amdgcn_mfma_f32_16x16x32_f16(ab[i], wb[i], acc[i & 3], 0, 0, 0);
  return (acc[0] + acc[1]) + (acc[2] + acc[3]);
}

__device__ inline void cast16v(const float* s, _Float16* d, size_t n, int gid, int gsz) {
  const float4* s4 = (const float4*)s;
  size_t n4 = n >> 2;
  for (size_t i = (size_t)gid; i < n4; i += (size_t)gsz) {
    float4 v = s4[i];
    h4v o = {(_Float16)v.x, (_Float16)v.y, (_Float16)v.z, (_Float16)v.w};
    *(h4v*)(d + 4 * i) = o;
  }
}

// ---- P1 tile: [0,128) sWa ; [128,512) gh ; [512,576) yi_emb ----
__device__ void p1_tile(int tile, const _Float16* yiPtr, const _Float16* si16,
                        const _Float16* WaF, const _Float16* WhhF, const _Float16* embF,
                        const float* bhh, const float* embb,
                        float* sWaF, float* ghF, _Float16* x16) {
  const int lane = threadIdx.x & 63;
  const int q = lane >> 4, c = lane & 15;
  f4 acc = {0.f, 0.f, 0.f, 0.f};
  if (tile < 128) {
    int n0 = (tile >> 1) << 4, m0 = (tile & 1) << 4;
    acc = gemm16p<8>(si16 + (size_t)m0 * HID, HID, WaF + (size_t)n0 * HID, HID, HID, acc);
    int col = n0 + c;
    for (int i = 0; i < 4; i++) sWaF[(size_t)(m0 + q * 4 + i) * HID + col] = acc[i];
  } else if (tile < 512) {
    int idx = tile - 128;
    int n0 = (idx >> 1) << 4, m0 = (idx & 1) << 4;
    acc = gemm16p<8>(si16 + (size_t)m0 * HID, HID, WhhF + (size_t)n0 * HID, HID, HID, acc);
    int col = n0 + c; float bb = bhh[col];
    for (int i = 0; i < 4; i++) ghF[(size_t)(m0 + q * 4 + i) * G3 + col] = acc[i] + bb;
  } else {
    int idx = tile - 512;
    int n0 = (idx >> 1) << 4, m0 = (idx & 1) << 4;
    acc = gemm16p<8>(yiPtr + (size_t)m0 * HID, HID, embF + (size_t)n0 * HID, HID, HID, acc);
    int col = n0 + c; float bb = embb[col];
    for (int i = 0; i < 4; i++)
      x16[(size_t)(m0 + q * 4 + i) * KX + col] = (_Float16)(acc[i] + bb);
  }
}

// ---- P5 tile: mo += si-part; maxout pairs -> m16 ----
__device__ void p5_tile(int tile, const _Float16* si16, const _Float16* moF,
                        const float* moP, _Float16* m16) {
  const int lane = threadIdx.x & 63;
  const int q = lane >> 4, c = lane & 15;
  int n0 = (tile >> 1) << 4, m0 = (tile & 1) << 4;
  int col = n0 + c;
  f4 acc;
  for (int i = 0; i < 4; i++) acc[i] = moP[(size_t)(m0 + q * 4 + i) * (2 * MOU) + col];
  acc = gemm16p<8>(si16 + (size_t)m0 * HID, HID, moF + (size_t)n0 * KMO, KMO, HID, acc);
  for (int i = 0; i < 4; i++) {
    float v = acc[i];
    float o = __shfl_xor(v, 1, 64);
    if ((lane & 1) == 0) {
      int row = m0 + q * 4 + i;
      m16[(size_t)row * MOU + (col >> 1)] = (_Float16)fmaxf(v, o);
    }
  }
}

// ---- P3: gx = x@Wih^T + bih ; moP = [ctx,yemb]-part of mo_in@mo_w^T + mob ----
__device__ void phase_P3(const _Float16* x16, const _Float16* WihF, const _Float16* moF,
                         const float* bih, const float* mob,
                         float* gxF, float* moP, int gw, int nwv) {
  const int lane = threadIdx.x & 63;
  const int q = lane >> 4, c = lane & 15;
  for (int tile = gw; tile < 512; tile += nwv) {
    f4 acc = {0.f, 0.f, 0.f, 0.f};
    if (tile < 384) {
      int n0 = (tile >> 1) << 4, m0 = (tile & 1) << 4;
      acc = gemm16p<8>(x16 + (size_t)m0 * KX, KX, WihF + (size_t)n0 * KX, KX, KX, acc);
      int col = n0 + c; float bb = bih[col];
      for (int i = 0; i < 4; i++) gxF[(size_t)(m0 + q * 4 + i) * G3 + col] = acc[i] + bb;
    } else {
      int idx = tile - 384;
      int n0 = (idx >> 1) << 4, m0 = (idx & 1) << 4;
      acc = gemm16p<8>(x16 + (size_t)m0 * KX + EMB, KX, moF + (size_t)n0 * KMO + HID, KMO, 2 * HID, acc);
      acc = gemm16p<8>(x16 + (size_t)m0 * KX, KX, moF + (size_t)n0 * KMO + 3 * HID, KMO, EMB, acc);
      int col = n0 + c; float bb = mob[col];
      for (int i = 0; i < 4; i++) moP[(size_t)(m0 + q * 4 + i) * (2 * MOU) + col] = acc[i] + bb;
    }
  }
}

// ---- fc: logits[b,t,:] = m@fc_w^T + fc_b. A from global (L1/L2-hot 32KB). ----
// Tile range [tile0, tileN) so the work can be placed in whichever phase has
// idle waves (fc(t-1) is legal anywhere in P2/P3/P4 of step t: m16 is not
// overwritten until P5(t)).
__device__ void fc_phase(const _Float16* m16g, const _Float16* fcF, const float* fcb,
                         float* out, int tstep, int w, int nw, int tile0, int tileN) {
  const int lane = threadIdx.x & 63;
  const int q = lane >> 4, l15 = lane & 15;
  const _Float16* a0 = m16g + (size_t)l15 * MOU + (q << 3);
  const _Float16* a1 = a0 + (size_t)16 * MOU;
  for (int tile = tile0 + w; tile < tileN; tile += nw) {
    int n0 = tile * 32;
    const _Float16* b0 = fcF + (size_t)(n0 + l15) * MOU + (q << 3);
    const _Float16* b1 = b0 + (size_t)16 * MOU;
    f4 z = {0.f, 0.f, 0.f, 0.f};
    f4 acc00 = z, acc01 = z, acc10 = z, acc11 = z;
    constexpr int PF = 4;
    h8 B0[PF], B1[PF];
#pragma unroll
    for (int i = 0; i < PF; i++) {
      B0[i] = *(const h8*)(b0 + 32 * i);
      B1[i] = *(const h8*)(b1 + 32 * i);
    }
    for (int kb = PF; kb < 16; kb += PF) {
#pragma unroll
      for (int i = 0; i < PF; i++) {
        h8 A0 = *(const h8*)(a0 + 32 * (kb - PF + i));
        h8 A1 = *(const h8*)(a1 + 32 * (kb - PF + i));
        h8 bb0 = B0[i], bb1 = B1[i];
        B0[i] = *(const h8*)(b0 + 32 * (kb + i));
        B1[i] = *(const h8*)(b1 + 32 * (kb + i));
        acc00 = __builtin_amdgcn_mfma_f32_16x16x32_f16(A0, bb0, acc00, 0, 0, 0);
        acc01 = __builtin_amdgcn_mfma_f32_16x16x32_f16(A0, bb1, acc01, 0, 0, 0);
        acc10 = __builtin_amdgcn_mfma_f32_16x16x32_f16(A1, bb0, acc10, 0, 0, 0);
        acc11 = __builtin_amdgcn_mfma_f32_16x16x32_f16(A1, bb1, acc11, 0, 0, 0);
      }
    }
#pragma unroll
    for (int i = 0; i < PF; i++) {
      h8 A0 = *(const h8*)(a0 + 32 * (16 - PF + i));
      h8 A1 = *(const h8*)(a1 + 32 * (16 - PF + i));
      acc00 = __builtin_amdgcn_mfma_f32_16x16x32_f16(A0, B0[i], acc00, 0, 0, 0);
      acc01 = __builtin_amdgcn_mfma_f32_16x16x32_f16(A0, B1[i], acc01, 0, 0, 0);
      acc10 = __builtin_amdgcn_mfma_f32_16x16x32_f16(A1, B0[i], acc10, 0, 0, 0);
      acc11 = __builtin_amdgcn_mfma_f32_16x16x32_f16(A1, B1[i], acc11, 0, 0, 0);
    }
    for (int ni = 0; ni < 2; ni++) {
      int v = n0 + ni * 16 + l15;
      float bias = fcb[v];
      f4 am0 = ni ? acc01 : acc00;
      f4 am1 = ni ? acc11 : acc10;
      for (int i = 0; i < 4; i++) {
        int br0 = q * 4 + i;
        out[((size_t)br0 * TSEQ + tstep) * VOC + v] = am0[i] + bias;
        out[((size_t)(br0 + 16) * TSEQ + tstep) * VOC + v] = am1[i] + bias;
      }
    }
  }
}

// ---- P2 attention for one batch row per block ----
__device__ void attention_phase(int t, const float* sWaF, const float* UaEnc,
                                const _Float16* encF, const float* va,
                                _Float16* x16, float* out,
                                float* sW, float* sva, float* sAl) {
  const int b = blockIdx.x;
  const int tid = threadIdx.x;
  for (int i = tid; i < HID / 4; i += NTHR) {
    *(f4*)(sW + 4 * i) = *(const f4*)(sWaF + (size_t)b * HID + 4 * i);
    *(f4*)(sva + 4 * i) = *(const f4*)(va + 4 * i);
  }
  __syncthreads();
  const int wid = tid >> 6, lane = tid & 63;
  for (int tt = wid; tt < TSEQ; tt += 4) {
    const float* ue = UaEnc + (size_t)(b * TSEQ + tt) * HID;
    float a = 0.f;
#pragma unroll
    for (int j = 0; j < 4; j++) {
      int h = (j * 64 + lane) * 4;
      f4 u = *(const f4*)(ue + h);
      f4 w = *(const f4*)(sW + h);
      f4 vv = *(const f4*)(sva + h);
      for (int e = 0; e < 4; e++) a += vv[e] * fast_tanh(w[e] + u[e]);
    }
    for (int off = 32; off; off >>= 1) a += __shfl_xor(a, off, 64);
    if (lane == 0) sAl[tt] = a;
  }
  __syncthreads();
  if (wid == 0) {
    float e = sAl[lane];
    float mx = e;
    for (int off = 32; off; off >>= 1) mx = fmaxf(mx, __shfl_xor(mx, off, 64));
    float p = __expf(e - mx);
    float s = p;
    for (int off = 32; off; off >>= 1) s += __shfl_xor(s, off, 64);
    float al = p / s;
    sAl[lane] = al;
    out[ALPHA_OFF + ((size_t)b * TSEQ + t) * TSEQ + lane] = al;
  }
  __syncthreads();
  for (int g = tid; g < (2 * HID) / 8; g += NTHR) {
    const _Float16* ep = encF + (size_t)b * TSEQ * 2 * HID + g * 8;
    f4 accA = {0.f, 0.f, 0.f, 0.f}, accB = {0.f, 0.f, 0.f, 0.f};
#pragma unroll 8
    for (int tt = 0; tt < TSEQ; tt++) {
      h8 v = *(const h8*)(ep + (size_t)tt * 2 * HID);
      float al = sAl[tt];
      accA[0] += al * (float)v[0]; accA[1] += al * (float)v[1];
      accA[2] += al * (float)v[2]; accA[3] += al * (float)v[3];
      accB[0] += al * (float)v[4]; accB[1] += al * (float)v[5];
      accB[2] += al * (float)v[6]; accB[3] += al * (float)v[7];
    }
    h8 o;
    o[0] = (_Float16)accA[0]; o[1] = (_Float16)accA[1];
    o[2] = (_Float16)accA[2]; o[3] = (_Float16)accA[3];
    o[4] = (_Float16)accB[0]; o[5] = (_Float16)accB[1];
    o[6] = (_Float16)accB[2]; o[7] = (_Float16)accB[3];
    *(h8*)(x16 + (size_t)b * KX + EMB + g * 8) = o;
  }
}

__global__ __launch_bounds__(NTHR, 2) void dec_kernel(
    const float* enc, const float* hid, const float* Wsw, const float* Wsb,
    const float* embw, const float* embb, const float* wih, const float* whh,
    const float* bih, const float* bhh, const float* Wa, const float* Ua,
    const float* va, const float* mow, const float* mob, const float* fcw,
    const float* fcb, float* out, unsigned char* ws) {
  __shared__ float sW[HID];
  __shared__ float sva[HID];
  __shared__ float sAl[TSEQ];

  unsigned* rel   = (unsigned*)ws;
  unsigned* flags = (unsigned*)(ws + 256);
  _Float16* WaF  = (_Float16*)(ws + BAR_BYTES);
  _Float16* WhhF = WaF + S_Wa;
  _Float16* WihF = WhhF + S_Whh;
  _Float16* embF = WihF + S_Wih;
  _Float16* UaF  = embF + S_emb;
  _Float16* moF  = UaF + S_Ua;
  _Float16* fcF  = moF + S_mo;
  _Float16* encF = fcF + S_fc;
  _Float16* si16 = encF + S_enc;
  _Float16* yi16 = si16 + (size_t)BSZ * HID;
  _Float16* x16  = yi16 + (size_t)BSZ * HID;
  _Float16* m16  = x16 + (size_t)BSZ * KX;
  float* UaEnc = (float*)(m16 + (size_t)BSZ * MOU);
  float* sWaF  = UaEnc + (size_t)BSZ * TSEQ * HID;
  float* ghF   = sWaF + (size_t)BSZ * HID;
  float* gxF   = ghF + (size_t)BSZ * G3;
  float* siF   = gxF + (size_t)BSZ * G3;
  float* moP   = siF + (size_t)BSZ * HID;

  const int tid = threadIdx.x;
  const int nb  = gridDim.x;
  const int gid = blockIdx.x * NTHR + tid;
  const int gsz = nb * NTHR;
  const int lane = tid & 63;
  const int wid = tid >> 6;
  const int gw = (blockIdx.x << 2) + wid;
  const int nwv = nb << 2;
  unsigned g = 0;

  // ---- phase 0: casts + si0 + zero yi ----
  cast16v(Wa, WaF, S_Wa, gid, gsz);
  cast16v(whh, WhhF, S_Whh, gid, gsz);
  cast16v(wih, WihF, S_Wih, gid, gsz);
  cast16v(embw, embF, S_emb, gid, gsz);
  cast16v(Ua, UaF, S_Ua, gid, gsz);
  cast16v(mow, moF, S_mo, gid, gsz);
  cast16v(fcw, fcF, S_fc, gid, gsz);
  cast16v(enc, encF, S_enc, gid, gsz);
  for (int i = gid; i < BSZ * HID; i += gsz) yi16[i] = (_Float16)0.f;
  for (int o = gw; o < BSZ * HID; o += nwv) {
    int b = o >> 10, h = o & (HID - 1);
    const float* hv = hid + ((size_t)BSZ + b) * HID;  // hidden_enc[1]
    const float* wr = Wsw + (size_t)h * HID;
    float a = 0.f;
    for (int k = lane; k < HID; k += 64) a += hv[k] * wr[k];
    for (int off = 32; off; off >>= 1) a += __shfl_xor(a, off, 64);
    if (lane == 0) {
      float v = fast_tanh(a + Wsb[h]);
      siF[o] = v;
      si16[o] = (_Float16)v;
    }
  }
  gbar(rel, flags, g++);

  // ---- pre: Ua_enc = enc@Ua^T + P1(t=0, yi=0) ----
  {
    const int q = lane >> 4, c = lane & 15;
    for (int tile = gw; tile < 8192; tile += nwv) {
      int tm = tile & 127, tn = tile >> 7;
      int r0 = tm << 4, n0 = tn << 4;
      f4 acc = {0.f, 0.f, 0.f, 0.f};
      acc = gemm16p<8>(encF + (size_t)r0 * (2 * HID), 2 * HID,
                       UaF + (size_t)n0 * (2 * HID), 2 * HID, 2 * HID, acc);
      int col = n0 + c;
      for (int i = 0; i < 4; i++)
        UaEnc[(size_t)(r0 + q * 4 + i) * HID + col] = acc[i];
    }
  }
  for (int tile = gw; tile < 576; tile += nwv)
    p1_tile(tile, yi16, si16, WaF, WhhF, embF, bhh, embb, sWaF, ghF, x16);
  gbar(rel, flags, g++);

  // ---- time loop: 4 phases/step ----
  for (int t = 0; t < TSEQ; t++) {
    // P2: attention(t) on blocks 0..31; everyone else idles (fc moved to P3)
    if (blockIdx.x < BSZ) attention_phase(t, sWaF, UaEnc, encF, va, x16, out, sW, sva, sAl);
    gbar(rel, flags, g++);
    // P3: gx + mo(ctx,yemb) partial on waves [0,512) ; fc(t-1) on idle waves
    phase_P3(x16, WihF, moF, bih, mob, gxF, moP, gw, nwv);
    if (t > 0 && gw >= 512)
      fc_phase(m16, fcF, fcb, out, t - 1, gw - 512, nwv - 512, 0, FC_TILES);
    gbar(rel, flags, g++);
    // P4: GRU gates -> si_new (vectorized x4)
    {
      int idx = gid;
      if (idx < BSZ * (HID / 4)) {
        int b = idx / (HID / 4), h4 = (idx % (HID / 4)) * 4;
        const float* gxr = gxF + (size_t)b * G3;
        const float* ghr = ghF + (size_t)b * G3;
        f4 gr = *(const f4*)(gxr + h4);
        f4 hr = *(const f4*)(ghr + h4);
        f4 gz = *(const f4*)(gxr + HID + h4);
        f4 hz = *(const f4*)(ghr + HID + h4);
        f4 gn = *(const f4*)(gxr + 2 * HID + h4);
        f4 hn = *(const f4*)(ghr + 2 * HID + h4);
        f4 s  = *(const f4*)(siF + (size_t)b * HID + h4);
        f4 sn;
        h4v sh;
        for (int j = 0; j < 4; j++) {
          float r = fast_sig(gr[j] + hr[j]);
          float z = fast_sig(gz[j] + hz[j]);
          float n = fast_tanh(gn[j] + r * hn[j]);
          sn[j] = (1.f - z) * n + z * s[j];
          sh[j] = (_Float16)sn[j];
        }
        *(f4*)(siF + (size_t)b * HID + h4) = sn;
        *(h4v*)(si16 + (size_t)b * HID + h4) = sh;
      }
    }
    gbar(rel, flags, g++);
    // P5 + P1(t+1): both depend only on si_new
    for (int tile = gw; tile < 704; tile += nwv) {
      if (tile < 128) p5_tile(tile, si16, moF, moP, m16);
      else if (t + 1 < TSEQ)
        p1_tile(tile - 128, si16, si16, WaF, WhhF, embF, bhh, embb, sWaF, ghF, x16);
    }
    gbar(rel, flags, g++);
  }
  // tail: fc for t = 63 over all blocks
  fc_phase(m16, fcF, fcb, out, TSEQ - 1, gw, nwv, 0, FC_TILES);
}

extern "C" void kernel_launch(void* const* d_in, const int* in_sizes, int n_in,
                              void* d_out, int out_size, void* d_ws, size_t ws_size,
                              hipStream_t stream) {
  (void)in_sizes; (void)n_in; (void)out_size; (void)ws_size;
  hipMemsetAsync(d_ws, 0, BAR_BYTES, stream);  // barrier flags/release
  const float* enc = (const float*)d_in[0];
  const float* hid = (const float*)d_in[1];
  const float* Wsw = (const float*)d_in[2];
  const float* Wsb = (const float*)d_in[3];
  const float* embw = (const float*)d_in[4];
  const float* embb = (const float*)d_in[5];
  const float* wih = (const float*)d_in[6];
  const float* whh = (const float*)d_in[7];
  const float* bih = (const float*)d_in[8];
  const float* bhh = (const float*)d_in[9];
  const float* Wa = (const float*)d_in[10];
  const float* Ua = (const float*)d_in[11];
  const float* va = (const float*)d_in[12];
  const float* mow = (const float*)d_in[13];
  const float* mob = (const float*)d_in[14];
  const float* fcw = (const float*)d_in[15];
  const float* fcb = (const float*)d_in[16];
  float* out = (float*)d_out;
  unsigned char* ws = (unsigned char*)d_ws;
  void* args[] = {&enc, &hid, &Wsw, &Wsb, &embw, &embb, &wih, &whh, &bih, &bhh,
                  &Wa, &Ua, &va, &mow, &mob, &fcw, &fcb, &out, &ws};
  int occ = 1;
  if (hipOccupancyMaxActiveBlocksPerMultiprocessor(&occ, dec_kernel, NTHR, 0) != hipSuccess || occ < 1)
    occ = 1;
  int grid = (occ >= 2) ? NBLK : 256;
  hipLaunchCooperativeKernel((void*)dec_kernel, dim3(grid), dim3(NTHR),
                             (void**)args, 0, stream);
}

// Round 4
// 7742.905 us; speedup vs baseline: 1.0473x; 1.0473x over previous
//
#include <hip/hip_runtime.h>
#include <hip/hip_fp16.h>

#define NBLK 512
#define NTHR 256

constexpr int BSZ = 32;
constexpr int TSEQ = 64;
constexpr int HID = 1024;
constexpr int EMB = 512;
constexpr int MOU = 512;     // M
constexpr int VOC = 32000;
constexpr int KX  = 2560;    // 2H + E (wih leading dim)
constexpr int KMO = 3584;    // 3H + E (mo_w leading dim)
constexpr int G3  = 3072;    // 3H
constexpr int FC_TILES = VOC / 32;   // 1000
constexpr size_t ALPHA_OFF = (size_t)BSZ * TSEQ * VOC;
// barrier region: 8 release copies 4KB apart (32KB) + 512 flag lines (32KB)
constexpr size_t BAR_BYTES = 65536;

constexpr size_t S_Wa   = (size_t)HID * HID;            // 1M
constexpr size_t S_Whh  = (size_t)G3 * HID;             // 3M
constexpr size_t S_Wih  = (size_t)G3 * KX;              // 7.86M (pre only)
constexpr size_t S_embT = (size_t)HID * EMB;            // 0.5M  (pre only)
constexpr size_t S_Ua   = (size_t)HID * 2 * HID;        // 2M    (pre only)
constexpr size_t S_mo   = (size_t)2 * MOU * KMO;        // 3.67M
constexpr size_t S_fc   = (size_t)VOC * MOU;            // 16.4M
constexpr size_t S_enc  = (size_t)BSZ * TSEQ * 2 * HID; // 4.19M (pre only)
constexpr size_t S_W1   = (size_t)G3 * HID;             // 3.1M
constexpr size_t S_W2   = (size_t)HID * HID;            // 1M
constexpr size_t S_eWM  = (size_t)BSZ * TSEQ * 4096;    // 8.39M (encW|encMo)

typedef _Float16 h8 __attribute__((ext_vector_type(8)));
typedef _Float16 h4v __attribute__((ext_vector_type(4)));
typedef float f4 __attribute__((ext_vector_type(4)));

__device__ inline float fast_tanh(float x) {
  float e = __expf(2.f * x);
  return (e - 1.f) / (e + 1.f);
}
__device__ inline float fast_sig(float x) { return 1.f / (1.f + __expf(-x)); }

// ---- distributed flag barrier, multi-line release ----
// rel copy i at ws_u + i*1024 (4KB apart -> distinct L3 slices); flags at
// ws_u + 8192 + bid*16. Block polls rel copy (bid & 7): release fan-out of
// 511 pollers spreads over 8 lines instead of hammering one.
__device__ inline void gbar(unsigned* ws_u, unsigned g) {
  unsigned* flags = ws_u + 8192;
  __syncthreads();
  if (blockIdx.x == 0) {
    if (threadIdx.x < 64) {
      const int lane = threadIdx.x;
      const int nb = gridDim.x;
      for (;;) {
        bool ok = true;
        for (int i = lane; i < nb; i += 64)
          if (i != 0)
            ok &= (__hip_atomic_load(flags + (size_t)i * 16, __ATOMIC_RELAXED,
                                     __HIP_MEMORY_SCOPE_AGENT) > g);
        if (__builtin_amdgcn_ballot_w64(ok) == ~0ull) break;
        __builtin_amdgcn_s_sleep(2);
      }
      __threadfence();
      if (lane < 8)
        __hip_atomic_store(ws_u + (size_t)lane * 1024, g + 1, __ATOMIC_RELAXED,
                           __HIP_MEMORY_SCOPE_AGENT);
    }
    __syncthreads();
  } else {
    if (threadIdx.x == 0) {
      __threadfence();
      __hip_atomic_store(flags + (size_t)blockIdx.x * 16, g + 1, __ATOMIC_RELAXED,
                         __HIP_MEMORY_SCOPE_AGENT);
      unsigned* myrel = ws_u + (size_t)(blockIdx.x & 7) * 1024;
      while (__hip_atomic_load(myrel, __ATOMIC_RELAXED, __HIP_MEMORY_SCOPE_AGENT) <= g)
        __builtin_amdgcn_s_sleep(2);
      __threadfence();
    }
    __syncthreads();
  }
}

// ---- pipelined 16x16 tile GEMM: C += A[16,klen] * W[16,klen]^T ----
template <int PF>
__device__ inline f4 gemm16p(const _Float16* A, int lda, const _Float16* W, int ldw,
                             int klen, f4 accin) {
  const int lane = threadIdx.x & 63;
  const _Float16* ap = A + (size_t)(lane & 15) * lda + ((lane >> 4) << 3);
  const _Float16* wp = W + (size_t)(lane & 15) * ldw + ((lane >> 4) << 3);
  const int nk = klen >> 5;
  f4 acc[4];
  acc[0] = accin;
  acc[1] = f4{0.f, 0.f, 0.f, 0.f};
  acc[2] = f4{0.f, 0.f, 0.f, 0.f};
  acc[3] = f4{0.f, 0.f, 0.f, 0.f};
  h8 ab[PF], wb[PF];
#pragma unroll
  for (int i = 0; i < PF; i++) {
    ab[i] = *(const h8*)(ap + 32 * i);
    wb[i] = *(const h8*)(wp + 32 * i);
  }
  for (int kb = PF; kb < nk; kb += PF) {
#pragma unroll
    for (int i = 0; i < PF; i++) {
      h8 a = ab[i], w = wb[i];
      ab[i] = *(const h8*)(ap + 32 * (kb + i));
      wb[i] = *(const h8*)(wp + 32 * (kb + i));
      acc[i & 3] = __builtin_amdgcn_mfma_f32_16x16x32_f16(a, w, acc[i & 3], 0, 0, 0);
    }
  }
#pragma unroll
  for (int i = 0; i < PF; i++)
    acc[i & 3] = __builtin_amdgcn_mfma_f32_16x16x32_f16(ab[i], wb[i], acc[i & 3], 0, 0, 0);
  return (acc[0] + acc[1]) + (acc[2] + acc[3]);
}

__device__ inline void cast16v(const float* s, _Float16* d, size_t n, int gid, int gsz) {
  const float4* s4 = (const float4*)s;
  size_t n4 = n >> 2;
  for (size_t i = (size_t)gid; i < n4; i += (size_t)gsz) {
    float4 v = s4[i];
    h4v o = {(_Float16)v.x, (_Float16)v.y, (_Float16)v.z, (_Float16)v.w};
    *(h4v*)(d + 4 * i) = o;
  }
}

// ---- alpha-phase GEMM tile: u<384 gh ; u<768 gxY=yi@W1^T ; else moY=yi@W2^T ----
__device__ void alpha_tile(int u, const _Float16* yiPtr, const _Float16* si16,
                           const _Float16* WhhF, const _Float16* W1F, const _Float16* W2F,
                           const float* bhh, const float* biasGx, const float* biasMo,
                           float* ghF, float* gxY, float* moY) {
  const int lane = threadIdx.x & 63;
  const int q = lane >> 4, c = lane & 15;
  f4 acc = {0.f, 0.f, 0.f, 0.f};
  if (u < 384) {
    int n0 = (u >> 1) << 4, m0 = (u & 1) << 4;
    acc = gemm16p<16>(si16 + (size_t)m0 * HID, HID, WhhF + (size_t)n0 * HID, HID, HID, acc);
    int col = n0 + c; float bb = bhh[col];
    for (int i = 0; i < 4; i++) ghF[(size_t)(m0 + q * 4 + i) * G3 + col] = acc[i] + bb;
  } else if (u < 768) {
    int idx = u - 384;
    int n0 = (idx >> 1) << 4, m0 = (idx & 1) << 4;
    acc = gemm16p<16>(yiPtr + (size_t)m0 * HID, HID, W1F + (size_t)n0 * HID, HID, HID, acc);
    int col = n0 + c; float bb = biasGx[col];
    for (int i = 0; i < 4; i++) gxY[(size_t)(m0 + q * 4 + i) * G3 + col] = acc[i] + bb;
  } else {
    int idx = u - 768;
    int n0 = (idx >> 1) << 4, m0 = (idx & 1) << 4;
    acc = gemm16p<16>(yiPtr + (size_t)m0 * HID, HID, W2F + (size_t)n0 * HID, HID, HID, acc);
    int col = n0 + c; float bb = biasMo[col];
    for (int i = 0; i < 4; i++) moY[(size_t)(m0 + q * 4 + i) * HID + col] = acc[i] + bb;
  }
}

// ---- gamma tile: tile<128 mo_si+maxout -> m16 ; else sWa(t+1) ----
__device__ void gamma_tile(int tile, const _Float16* si16, const _Float16* moF,
                           const _Float16* WaF, const float* moC, const float* moY,
                           float* sWaF, _Float16* m16) {
  const int lane = threadIdx.x & 63;
  const int q = lane >> 4, c = lane & 15;
  if (tile < 128) {
    int n0 = (tile >> 1) << 4, m0 = (tile & 1) << 4;
    int col = n0 + c;
    f4 acc;
    for (int i = 0; i < 4; i++) {
      size_t r = (size_t)(m0 + q * 4 + i) * HID + col;
      acc[i] = moC[r] + moY[r];
    }
    acc = gemm16p<16>(si16 + (size_t)m0 * HID, HID, moF + (size_t)n0 * KMO, KMO, HID, acc);
    for (int i = 0; i < 4; i++) {
      float v = acc[i];
      float o = __shfl_xor(v, 1, 64);
      if ((lane & 1) == 0) {
        int row = m0 + q * 4 + i;
        m16[(size_t)row * MOU + (col >> 1)] = (_Float16)fmaxf(v, o);
      }
    }
  } else {
    int idx = tile - 128;
    int n0 = (idx >> 1) << 4, m0 = (idx & 1) << 4;
    f4 acc = {0.f, 0.f, 0.f, 0.f};
    acc = gemm16p<16>(si16 + (size_t)m0 * HID, HID, WaF + (size_t)n0 * HID, HID, HID, acc);
    int col = n0 + c;
    for (int i = 0; i < 4; i++) sWaF[(size_t)(m0 + q * 4 + i) * HID + col] = acc[i];
  }
}

// ---- one fc tile (32 vocab cols): logits[:, tstep, n0:n0+32] ----
__device__ void fc_tile(int tile, const _Float16* m16g, const _Float16* fcF,
                        const float* fcb, float* out, int tstep) {
  const int lane = threadIdx.x & 63;
  const int q = lane >> 4, l15 = lane & 15;
  const _Float16* a0 = m16g + (size_t)l15 * MOU + (q << 3);
  const _Float16* a1 = a0 + (size_t)16 * MOU;
  int n0 = tile * 32;
  const _Float16* b0 = fcF + (size_t)(n0 + l15) * MOU + (q << 3);
  const _Float16* b1 = b0 + (size_t)16 * MOU;
  f4 z = {0.f, 0.f, 0.f, 0.f};
  f4 acc00 = z, acc01 = z, acc10 = z, acc11 = z;
  constexpr int PF = 4;
  h8 B0[PF], B1[PF];
#pragma unroll
  for (int i = 0; i < PF; i++) {
    B0[i] = *(const h8*)(b0 + 32 * i);
    B1[i] = *(const h8*)(b1 + 32 * i);
  }
  for (int kb = PF; kb < 16; kb += PF) {
#pragma unroll
    for (int i = 0; i < PF; i++) {
      h8 A0 = *(const h8*)(a0 + 32 * (kb - PF + i));
      h8 A1 = *(const h8*)(a1 + 32 * (kb - PF + i));
      h8 bb0 = B0[i], bb1 = B1[i];
      B0[i] = *(const h8*)(b0 + 32 * (kb + i));
      B1[i] = *(const h8*)(b1 + 32 * (kb + i));
      acc00 = __builtin_amdgcn_mfma_f32_16x16x32_f16(A0, bb0, acc00, 0, 0, 0);
      acc01 = __builtin_amdgcn_mfma_f32_16x16x32_f16(A0, bb1, acc01, 0, 0, 0);
      acc10 = __builtin_amdgcn_mfma_f32_16x16x32_f16(A1, bb0, acc10, 0, 0, 0);
      acc11 = __builtin_amdgcn_mfma_f32_16x16x32_f16(A1, bb1, acc11, 0, 0, 0);
    }
  }
#pragma unroll
  for (int i = 0; i < PF; i++) {
    h8 A0 = *(const h8*)(a0 + 32 * (16 - PF + i));
    h8 A1 = *(const h8*)(a1 + 32 * (16 - PF + i));
    acc00 = __builtin_amdgcn_mfma_f32_16x16x32_f16(A0, B0[i], acc00, 0, 0, 0);
    acc01 = __builtin_amdgcn_mfma_f32_16x16x32_f16(A0, B1[i], acc01, 0, 0, 0);
    acc10 = __builtin_amdgcn_mfma_f32_16x16x32_f16(A1, B0[i], acc10, 0, 0, 0);
    acc11 = __builtin_amdgcn_mfma_f32_16x16x32_f16(A1, B1[i], acc11, 0, 0, 0);
  }
  for (int ni = 0; ni < 2; ni++) {
    int v = n0 + ni * 16 + l15;
    float bias = fcb[v];
    f4 am0 = ni ? acc01 : acc00;
    f4 am1 = ni ? acc11 : acc10;
    for (int i = 0; i < 4; i++) {
      int br0 = q * 4 + i;
      out[((size_t)br0 * TSEQ + tstep) * VOC + v] = am0[i] + bias;
      out[((size_t)(br0 + 16) * TSEQ + tstep) * VOC + v] = am1[i] + bias;
    }
  }
}

// ---- alpha-phase attention for one batch row per block ----
// escore/softmax as before; then gx_ctx/moP_ctx = alpha-weighted row sums of
// the precomputed eWM = [enc@Wih_ctx^T | enc@mo_ctx^T] (f16, 4096 cols).
__device__ void attention_alpha(int t, const float* sWaF, const float* UaEnc,
                                const _Float16* eWM, const float* va,
                                float* gxC, float* moC, float* out,
                                float* sW, float* sva, float* sAl) {
  const int b = blockIdx.x;
  const int tid = threadIdx.x;
  for (int i = tid; i < HID / 4; i += NTHR) {
    *(f4*)(sW + 4 * i) = *(const f4*)(sWaF + (size_t)b * HID + 4 * i);
    *(f4*)(sva + 4 * i) = *(const f4*)(va + 4 * i);
  }
  __syncthreads();
  const int wid = tid >> 6, lane = tid & 63;
  for (int tt = wid; tt < TSEQ; tt += 4) {
    const float* ue = UaEnc + (size_t)(b * TSEQ + tt) * HID;
    float a = 0.f;
#pragma unroll
    for (int j = 0; j < 4; j++) {
      int h = (j * 64 + lane) * 4;
      f4 u = *(const f4*)(ue + h);
      f4 w = *(const f4*)(sW + h);
      f4 vv = *(const f4*)(sva + h);
      for (int e = 0; e < 4; e++) a += vv[e] * fast_tanh(w[e] + u[e]);
    }
    for (int off = 32; off; off >>= 1) a += __shfl_xor(a, off, 64);
    if (lane == 0) sAl[tt] = a;
  }
  __syncthreads();
  if (wid == 0) {
    float e = sAl[lane];
    float mx = e;
    for (int off = 32; off; off >>= 1) mx = fmaxf(mx, __shfl_xor(mx, off, 64));
    float p = __expf(e - mx);
    float s = p;
    for (int off = 32; off; off >>= 1) s += __shfl_xor(s, off, 64);
    float al = p / s;
    sAl[lane] = al;
    out[ALPHA_OFF + ((size_t)b * TSEQ + t) * TSEQ + lane] = al;
  }
  __syncthreads();
  // weighted row sums: 4096 cols, 8 per h8 group; 512 groups over 256 threads
  for (int g = tid; g < 512; g += NTHR) {
    const _Float16* ep = eWM + (size_t)b * TSEQ * 4096 + g * 8;
    f4 accA = {0.f, 0.f, 0.f, 0.f}, accB = {0.f, 0.f, 0.f, 0.f};
#pragma unroll 8
    for (int tt = 0; tt < TSEQ; tt++) {
      h8 v = *(const h8*)(ep + (size_t)tt * 4096);
      float al = sAl[tt];
      accA[0] += al * (float)v[0]; accA[1] += al * (float)v[1];
      accA[2] += al * (float)v[2]; accA[3] += al * (float)v[3];
      accB[0] += al * (float)v[4]; accB[1] += al * (float)v[5];
      accB[2] += al * (float)v[6]; accB[3] += al * (float)v[7];
    }
    int c0 = g * 8;
    float* dst = (c0 < G3) ? (gxC + (size_t)b * G3 + c0)
                           : (moC + (size_t)b * HID + (c0 - G3));
    *(f4*)dst = accA;
    *(f4*)(dst + 4) = accB;
  }
}

__global__ __launch_bounds__(NTHR, 2) void dec_kernel(
    const float* enc, const float* hid, const float* Wsw, const float* Wsb,
    const float* embw, const float* embb, const float* wih, const float* whh,
    const float* bih, const float* bhh, const float* Wa, const float* Ua,
    const float* va, const float* mow, const float* mob, const float* fcw,
    const float* fcb, float* out, unsigned char* ws) {
  __shared__ float sW[HID];
  __shared__ float sva[HID];
  __shared__ float sAl[TSEQ];

  unsigned* ws_u = (unsigned*)ws;
  _Float16* WaF  = (_Float16*)(ws + BAR_BYTES);
  _Float16* WhhF = WaF + S_Wa;
  _Float16* WihF = WhhF + S_Whh;
  _Float16* embT = WihF + S_Wih;
  _Float16* UaF  = embT + S_embT;
  _Float16* moF  = UaF + S_Ua;
  _Float16* fcF  = moF + S_mo;
  _Float16* encF = fcF + S_fc;
  _Float16* W1F  = encF + S_enc;
  _Float16* W2F  = W1F + S_W1;
  _Float16* eWM  = W2F + S_W2;
  _Float16* si16 = eWM + S_eWM;
  _Float16* yi16 = si16 + (size_t)BSZ * HID;
  _Float16* m16  = yi16 + (size_t)BSZ * HID;
  float* UaEnc  = (float*)(m16 + (size_t)BSZ * MOU);
  float* gxC    = UaEnc + (size_t)BSZ * TSEQ * HID;
  float* gxY    = gxC + (size_t)BSZ * G3;
  float* ghF    = gxY + (size_t)BSZ * G3;
  float* moC    = ghF + (size_t)BSZ * G3;
  float* moY    = moC + (size_t)BSZ * HID;
  float* siF    = moY + (size_t)BSZ * HID;
  float* sWaF   = siF + (size_t)BSZ * HID;
  float* biasGx = sWaF + (size_t)BSZ * HID;
  float* biasMo = biasGx + G3;

  const int tid = threadIdx.x;
  const int nb  = gridDim.x;
  const int gid = blockIdx.x * NTHR + tid;
  const int gsz = nb * NTHR;
  const int lane = tid & 63;
  const int wid = tid >> 6;
  const int gw = (blockIdx.x << 2) + wid;
  const int nwv = nb << 2;
  unsigned g = 0;

  // ---- phase 0: casts + si0 + embT + bias folds ----
  cast16v(Wa, WaF, S_Wa, gid, gsz);
  cast16v(whh, WhhF, S_Whh, gid, gsz);
  cast16v(wih, WihF, S_Wih, gid, gsz);
  cast16v(Ua, UaF, S_Ua, gid, gsz);
  cast16v(mow, moF, S_mo, gid, gsz);
  cast16v(fcw, fcF, S_fc, gid, gsz);
  cast16v(enc, encF, S_enc, gid, gsz);
  // embT[h][e] = emb_w[e][h]
  for (int i = gid; i < EMB * HID; i += gsz) {
    int e = i >> 10, h = i & (HID - 1);
    embT[(size_t)h * EMB + e] = (_Float16)embw[i];
  }
  for (int i = gid; i < BSZ * HID; i += gsz) yi16[i] = (_Float16)0.f;
  // si0
  for (int o = gw; o < BSZ * HID; o += nwv) {
    int b = o >> 10, h = o & (HID - 1);
    const float* hv = hid + ((size_t)BSZ + b) * HID;  // hidden_enc[1]
    const float* wr = Wsw + (size_t)h * HID;
    float a = 0.f;
    for (int k = lane; k < HID; k += 64) a += hv[k] * wr[k];
    for (int off = 32; off; off >>= 1) a += __shfl_xor(a, off, 64);
    if (lane == 0) {
      float v = fast_tanh(a + Wsb[h]);
      siF[o] = v;
      si16[o] = (_Float16)v;
    }
  }
  // biasGx[n] = Wih_ye[n,:]@emb_b + bih[n] ; biasMo[n] = mo_ye[n,:]@emb_b + mob[n]
  for (int o = gw; o < G3 + HID; o += nwv) {
    const float* wr;
    if (o < G3) wr = wih + (size_t)o * KX;                      // cols [0,512)
    else        wr = mow + (size_t)(o - G3) * KMO + 3 * HID;    // cols [3072,3584)
    float a = 0.f;
    for (int k = lane; k < EMB; k += 64) a += wr[k] * embb[k];
    for (int off = 32; off; off >>= 1) a += __shfl_xor(a, off, 64);
    if (lane == 0) {
      if (o < G3) biasGx[o] = a + bih[o];
      else        biasMo[o - G3] = a + mob[o - G3];
    }
  }
  gbar(ws_u, g++);

  // ---- pre1: UaEnc, eWM, W1, W2, sWa(0) ----
  {
    const int q = lane >> 4, c = lane & 15;
    for (int tile = gw; tile < 57472; tile += nwv) {
      if (tile < 8192) {                       // UaEnc = enc@Ua^T (f32)
        int tm = tile & 127, tn = tile >> 7;
        int r0 = tm << 4, n0 = tn << 4;
        f4 acc = {0.f, 0.f, 0.f, 0.f};
        acc = gemm16p<8>(encF + (size_t)r0 * (2 * HID), 2 * HID,
                         UaF + (size_t)n0 * (2 * HID), 2 * HID, 2 * HID, acc);
        int col = n0 + c;
        for (int i = 0; i < 4; i++)
          UaEnc[(size_t)(r0 + q * 4 + i) * HID + col] = acc[i];
      } else if (tile < 40960) {               // eWM = [enc@Wih_ctx^T | enc@mo_ctx^T]
        int idx = tile - 8192;
        int r0 = (idx >> 8) << 4, n0 = (idx & 255) << 4;
        const _Float16* Bp; int ldb;
        if (n0 < G3) { Bp = WihF + (size_t)n0 * KX + EMB; ldb = KX; }
        else         { Bp = moF + (size_t)(n0 - G3) * KMO + HID; ldb = KMO; }
        f4 acc = {0.f, 0.f, 0.f, 0.f};
        acc = gemm16p<8>(encF + (size_t)r0 * (2 * HID), 2 * HID, Bp, ldb, 2 * HID, acc);
        int col = n0 + c;
        for (int i = 0; i < 4; i++)
          eWM[(size_t)(r0 + q * 4 + i) * 4096 + col] = (_Float16)acc[i];
      } else if (tile < 53248) {               // W1[n,h] = Wih_ye[n,:]@embT[h,:]
        int idx = tile - 40960;
        int n0 = (idx >> 6) << 4, h0 = (idx & 63) << 4;
        f4 acc = {0.f, 0.f, 0.f, 0.f};
        acc = gemm16p<8>(WihF + (size_t)n0 * KX, KX, embT + (size_t)h0 * EMB, EMB, EMB, acc);
        int col = h0 + c;
        for (int i = 0; i < 4; i++)
          W1F[(size_t)(n0 + q * 4 + i) * HID + col] = (_Float16)acc[i];
      } else if (tile < 57344) {               // W2[n,h] = mo_ye[n,:]@embT[h,:]
        int idx = tile - 53248;
        int n0 = (idx >> 6) << 4, h0 = (idx & 63) << 4;
        f4 acc = {0.f, 0.f, 0.f, 0.f};
        acc = gemm16p<8>(moF + (size_t)n0 * KMO + 3 * HID, KMO,
                         embT + (size_t)h0 * EMB, EMB, EMB, acc);
        int col = h0 + c;
        for (int i = 0; i < 4; i++)
          W2F[(size_t)(n0 + q * 4 + i) * HID + col] = (_Float16)acc[i];
      } else {                                 // sWa(0) = si0@Wa^T
        int idx = tile - 57344;
        int n0 = (idx >> 1) << 4, m0 = (idx & 1) << 4;
        f4 acc = {0.f, 0.f, 0.f, 0.f};
        acc = gemm16p<8>(si16 + (size_t)m0 * HID, HID, WaF + (size_t)n0 * HID, HID, HID, acc);
        int col = n0 + c;
        for (int i = 0; i < 4; i++)
          sWaF[(size_t)(m0 + q * 4 + i) * HID + col] = acc[i];
      }
    }
  }
  gbar(ws_u, g++);

  // ---- time loop: 3 phases/step ----
  for (int t = 0; t < TSEQ; t++) {
    // alpha: attention(t) on blocks 0..31 ; gh/gxY/moY tiles + fc(t-1) elsewhere
    if (blockIdx.x < BSZ) {
      attention_alpha(t, sWaF, UaEnc, eWM, va, gxC, moC, out, sW, sva, sAl);
    } else {
      const _Float16* yiPtr = (t == 0) ? yi16 : si16;
      int units = (t > 0) ? 1896 : 896;
      for (int u = gw - 128; u < units; u += nwv - 128) {
        if (u < 896)
          alpha_tile(u, yiPtr, si16, WhhF, W1F, W2F, bhh, biasGx, biasMo, ghF, gxY, moY);
        else
          fc_tile(u - 896, m16, fcF, fcb, out, t - 1);
      }
    }
    gbar(ws_u, g++);
    // beta: GRU -> si_new
    if (gid < BSZ * (HID / 4)) {
      int b = gid >> 8, h4 = (gid & 255) * 4;
      const float* gc = gxC + (size_t)b * G3;
      const float* gy = gxY + (size_t)b * G3;
      const float* gh = ghF + (size_t)b * G3;
      f4 gr = *(const f4*)(gc + h4) + *(const f4*)(gy + h4);
      f4 hr = *(const f4*)(gh + h4);
      f4 gz = *(const f4*)(gc + HID + h4) + *(const f4*)(gy + HID + h4);
      f4 hz = *(const f4*)(gh + HID + h4);
      f4 gn = *(const f4*)(gc + 2 * HID + h4) + *(const f4*)(gy + 2 * HID + h4);
      f4 hn = *(const f4*)(gh + 2 * HID + h4);
      f4 s  = *(const f4*)(siF + (size_t)b * HID + h4);
      f4 sn;
      h4v sh;
      for (int j = 0; j < 4; j++) {
        float r = fast_sig(gr[j] + hr[j]);
        float z = fast_sig(gz[j] + hz[j]);
        float n = fast_tanh(gn[j] + r * hn[j]);
        sn[j] = (1.f - z) * n + z * s[j];
        sh[j] = (_Float16)sn[j];
      }
      *(f4*)(siF + (size_t)b * HID + h4) = sn;
      *(h4v*)(si16 + (size_t)b * HID + h4) = sh;
    }
    gbar(ws_u, g++);
    // gamma: mo_si+maxout -> m16 ; sWa(t+1)
    {
      int lim = (t + 1 < TSEQ) ? 256 : 128;
      for (int tile = gw; tile < lim; tile += nwv)
        gamma_tile(tile, si16, moF, WaF, moC, moY, sWaF, m16);
    }
    gbar(ws_u, g++);
  }
  // tail: fc for t = 63 over all waves
  for (int tile = gw; tile < FC_TILES; tile += nwv)
    fc_tile(tile, m16, fcF, fcb, out, TSEQ - 1);
}

extern "C" void kernel_launch(void* const* d_in, const int* in_sizes, int n_in,
                              void* d_out, int out_size, void* d_ws, size_t ws_size,
                              hipStream_t stream) {
  (void)in_sizes; (void)n_in; (void)out_size; (void)ws_size;
  hipMemsetAsync(d_ws, 0, BAR_BYTES, stream);  // barrier flags/release
  const float* enc = (const float*)d_in[0];
  const float* hid = (const float*)d_in[1];
  const float* Wsw = (const float*)d_in[2];
  const float* Wsb = (const float*)d_in[3];
  const float* embw = (const float*)d_in[4];
  const float* embb = (const float*)d_in[5];
  const float* wih = (const float*)d_in[6];
  const float* whh = (const float*)d_in[7];
  const float* bih = (const float*)d_in[8];
  const float* bhh = (const float*)d_in[9];
  const float* Wa = (const float*)d_in[10];
  const float* Ua = (const float*)d_in[11];
  const float* va = (const float*)d_in[12];
  const float* mow = (const float*)d_in[13];
  const float* mob = (const float*)d_in[14];
  const float* fcw = (const float*)d_in[15];
  const float* fcb = (const float*)d_in[16];
  float* out = (float*)d_out;
  unsigned char* ws = (unsigned char*)d_ws;
  void* args[] = {&enc, &hid, &Wsw, &Wsb, &embw, &embb, &wih, &whh, &bih, &bhh,
                  &Wa, &Ua, &va, &mow, &mob, &fcw, &fcb, &out, &ws};
  int occ = 1;
  if (hipOccupancyMaxActiveBlocksPerMultiprocessor(&occ, dec_kernel, NTHR, 0) != hipSuccess || occ < 1)
    occ = 1;
  int grid = (occ >= 2) ? NBLK : 256;
  hipLaunchCooperativeKernel((void*)dec_kernel, dim3(grid), dim3(NTHR),
                             (void**)args, 0, stream);
}

// Round 6
// 5991.357 us; speedup vs baseline: 1.3534x; 1.2923x over previous
//
#include <hip/hip_runtime.h>
#include <hip/hip_fp16.h>

#define NBLK 512
#define NTHR 256

constexpr int BSZ = 32;
constexpr int TSEQ = 64;
constexpr int HID = 1024;
constexpr int EMB = 512;
constexpr int MOU = 512;     // M
constexpr int VOC = 32000;
constexpr int KX  = 2560;    // 2H + E (wih leading dim)
constexpr int KMO = 3584;    // 3H + E (mo_w leading dim)
constexpr int G3  = 3072;    // 3H
constexpr int FC_TILES = VOC / 32;   // 1000
constexpr size_t ALPHA_OFF = (size_t)BSZ * TSEQ * VOC;
// barrier region: 8 release copies 4KB apart (32KB) + 512 flag lines (32KB)
constexpr size_t BAR_BYTES = 65536;

constexpr size_t S_Wa   = (size_t)HID * HID;            // 1M
constexpr size_t S_Whh  = (size_t)G3 * HID;             // 3M
constexpr size_t S_Wih  = (size_t)G3 * KX;              // 7.86M (pre only)
constexpr size_t S_embT = (size_t)HID * EMB;            // 0.5M  (pre only)
constexpr size_t S_Ua   = (size_t)HID * 2 * HID;        // 2M    (pre only)
constexpr size_t S_mo   = (size_t)2 * MOU * KMO;        // 3.67M
constexpr size_t S_fc   = (size_t)VOC * MOU;            // 16.4M
constexpr size_t S_enc  = (size_t)BSZ * TSEQ * 2 * HID; // 4.19M (pre only)
constexpr size_t S_W1   = (size_t)G3 * HID;             // 3.1M
constexpr size_t S_W2   = (size_t)HID * HID;            // 1M
constexpr size_t S_eWM  = (size_t)BSZ * TSEQ * 4096;    // 8.39M (encW|encMo)

typedef _Float16 h8 __attribute__((ext_vector_type(8)));
typedef _Float16 h4v __attribute__((ext_vector_type(4)));
typedef float f4 __attribute__((ext_vector_type(4)));

__device__ inline float fast_tanh(float x) {
  float e = __expf(2.f * x);
  return (e - 1.f) / (e + 1.f);
}
__device__ inline float fast_sig(float x) { return 1.f / (1.f + __expf(-x)); }

// ---- distributed flag barrier, multi-line release ----
__device__ inline void gbar(unsigned* ws_u, unsigned g) {
  unsigned* flags = ws_u + 8192;
  __syncthreads();
  if (blockIdx.x == 0) {
    if (threadIdx.x < 64) {
      const int lane = threadIdx.x;
      const int nb = gridDim.x;
      for (;;) {
        bool ok = true;
        for (int i = lane; i < nb; i += 64)
          if (i != 0)
            ok &= (__hip_atomic_load(flags + (size_t)i * 16, __ATOMIC_RELAXED,
                                     __HIP_MEMORY_SCOPE_AGENT) > g);
        if (__builtin_amdgcn_ballot_w64(ok) == ~0ull) break;
        __builtin_amdgcn_s_sleep(2);
      }
      __threadfence();
      if (lane < 8)
        __hip_atomic_store(ws_u + (size_t)lane * 1024, g + 1, __ATOMIC_RELAXED,
                           __HIP_MEMORY_SCOPE_AGENT);
    }
    __syncthreads();
  } else {
    if (threadIdx.x == 0) {
      __threadfence();
      __hip_atomic_store(flags + (size_t)blockIdx.x * 16, g + 1, __ATOMIC_RELAXED,
                         __HIP_MEMORY_SCOPE_AGENT);
      unsigned* myrel = ws_u + (size_t)(blockIdx.x & 7) * 1024;
      while (__hip_atomic_load(myrel, __ATOMIC_RELAXED, __HIP_MEMORY_SCOPE_AGENT) <= g)
        __builtin_amdgcn_s_sleep(2);
      __threadfence();
    }
    __syncthreads();
  }
}

// ---- pipelined 16x16 tile GEMM: C += A[16,klen] * W[16,klen]^T ----
template <int PF>
__device__ inline f4 gemm16p(const _Float16* A, int lda, const _Float16* W, int ldw,
                             int klen, f4 accin) {
  const int lane = threadIdx.x & 63;
  const _Float16* ap = A + (size_t)(lane & 15) * lda + ((lane >> 4) << 3);
  const _Float16* wp = W + (size_t)(lane & 15) * ldw + ((lane >> 4) << 3);
  const int nk = klen >> 5;
  f4 acc[4];
  acc[0] = accin;
  acc[1] = f4{0.f, 0.f, 0.f, 0.f};
  acc[2] = f4{0.f, 0.f, 0.f, 0.f};
  acc[3] = f4{0.f, 0.f, 0.f, 0.f};
  h8 ab[PF], wb[PF];
#pragma unroll
  for (int i = 0; i < PF; i++) {
    ab[i] = *(const h8*)(ap + 32 * i);
    wb[i] = *(const h8*)(wp + 32 * i);
  }
  for (int kb = PF; kb < nk; kb += PF) {
#pragma unroll
    for (int i = 0; i < PF; i++) {
      h8 a = ab[i], w = wb[i];
      ab[i] = *(const h8*)(ap + 32 * (kb + i));
      wb[i] = *(const h8*)(wp + 32 * (kb + i));
      acc[i & 3] = __builtin_amdgcn_mfma_f32_16x16x32_f16(a, w, acc[i & 3], 0, 0, 0);
    }
  }
#pragma unroll
  for (int i = 0; i < PF; i++)
    acc[i & 3] = __builtin_amdgcn_mfma_f32_16x16x32_f16(ab[i], wb[i], acc[i & 3], 0, 0, 0);
  return (acc[0] + acc[1]) + (acc[2] + acc[3]);
}

__device__ inline void cast16v(const float* s, _Float16* d, size_t n, int gid, int gsz) {
  const float4* s4 = (const float4*)s;
  size_t n4 = n >> 2;
  for (size_t i = (size_t)gid; i < n4; i += (size_t)gsz) {
    float4 v = s4[i];
    h4v o = {(_Float16)v.x, (_Float16)v.y, (_Float16)v.z, (_Float16)v.w};
    *(h4v*)(d + 4 * i) = o;
  }
}

// ---- alpha-phase GEMM tile: u<384 gh ; u<768 gxY=yi@W1^T ; else moY=yi@W2^T ----
__device__ void alpha_tile(int u, const _Float16* yiPtr, const _Float16* si16,
                           const _Float16* WhhF, const _Float16* W1F, const _Float16* W2F,
                           const float* bhh, const float* biasGx, const float* biasMo,
                           float* ghF, float* gxY, float* moY) {
  const int lane = threadIdx.x & 63;
  const int q = lane >> 4, c = lane & 15;
  f4 acc = {0.f, 0.f, 0.f, 0.f};
  if (u < 384) {
    int n0 = (u >> 1) << 4, m0 = (u & 1) << 4;
    acc = gemm16p<16>(si16 + (size_t)m0 * HID, HID, WhhF + (size_t)n0 * HID, HID, HID, acc);
    int col = n0 + c; float bb = bhh[col];
    for (int i = 0; i < 4; i++) ghF[(size_t)(m0 + q * 4 + i) * G3 + col] = acc[i] + bb;
  } else if (u < 768) {
    int idx = u - 384;
    int n0 = (idx >> 1) << 4, m0 = (idx & 1) << 4;
    acc = gemm16p<16>(yiPtr + (size_t)m0 * HID, HID, W1F + (size_t)n0 * HID, HID, HID, acc);
    int col = n0 + c; float bb = biasGx[col];
    for (int i = 0; i < 4; i++) gxY[(size_t)(m0 + q * 4 + i) * G3 + col] = acc[i] + bb;
  } else {
    int idx = u - 768;
    int n0 = (idx >> 1) << 4, m0 = (idx & 1) << 4;
    acc = gemm16p<16>(yiPtr + (size_t)m0 * HID, HID, W2F + (size_t)n0 * HID, HID, HID, acc);
    int col = n0 + c; float bb = biasMo[col];
    for (int i = 0; i < 4; i++) moY[(size_t)(m0 + q * 4 + i) * HID + col] = acc[i] + bb;
  }
}

// ---- gamma tile: tile<128 mo_si+maxout -> m16 ; else sWa(t+1) ----
__device__ void gamma_tile(int tile, const _Float16* si16, const _Float16* moF,
                           const _Float16* WaF, const float* moC, const float* moY,
                           float* sWaF, _Float16* m16) {
  const int lane = threadIdx.x & 63;
  const int q = lane >> 4, c = lane & 15;
  if (tile < 128) {
    int n0 = (tile >> 1) << 4, m0 = (tile & 1) << 4;
    int col = n0 + c;
    f4 acc;
    for (int i = 0; i < 4; i++) {
      size_t r = (size_t)(m0 + q * 4 + i) * HID + col;
      acc[i] = moC[r] + moY[r];
    }
    acc = gemm16p<16>(si16 + (size_t)m0 * HID, HID, moF + (size_t)n0 * KMO, KMO, HID, acc);
    for (int i = 0; i < 4; i++) {
      float v = acc[i];
      float o = __shfl_xor(v, 1, 64);
      if ((lane & 1) == 0) {
        int row = m0 + q * 4 + i;
        m16[(size_t)row * MOU + (col >> 1)] = (_Float16)fmaxf(v, o);
      }
    }
  } else {
    int idx = tile - 128;
    int n0 = (idx >> 1) << 4, m0 = (idx & 1) << 4;
    f4 acc = {0.f, 0.f, 0.f, 0.f};
    acc = gemm16p<16>(si16 + (size_t)m0 * HID, HID, WaF + (size_t)n0 * HID, HID, HID, acc);
    int col = n0 + c;
    for (int i = 0; i < 4; i++) sWaF[(size_t)(m0 + q * 4 + i) * HID + col] = acc[i];
  }
}

// ---- one fc tile (32 vocab cols): logits[:, tstep, n0:n0+32] ----
__device__ void fc_tile(int tile, const _Float16* m16g, const _Float16* fcF,
                        const float* fcb, float* out, int tstep) {
  const int lane = threadIdx.x & 63;
  const int q = lane >> 4, l15 = lane & 15;
  const _Float16* a0 = m16g + (size_t)l15 * MOU + (q << 3);
  const _Float16* a1 = a0 + (size_t)16 * MOU;
  int n0 = tile * 32;
  const _Float16* b0 = fcF + (size_t)(n0 + l15) * MOU + (q << 3);
  const _Float16* b1 = b0 + (size_t)16 * MOU;
  f4 z = {0.f, 0.f, 0.f, 0.f};
  f4 acc00 = z, acc01 = z, acc10 = z, acc11 = z;
  constexpr int PF = 4;
  h8 B0[PF], B1[PF];
#pragma unroll
  for (int i = 0; i < PF; i++) {
    B0[i] = *(const h8*)(b0 + 32 * i);
    B1[i] = *(const h8*)(b1 + 32 * i);
  }
  for (int kb = PF; kb < 16; kb += PF) {
#pragma unroll
    for (int i = 0; i < PF; i++) {
      h8 A0 = *(const h8*)(a0 + 32 * (kb - PF + i));
      h8 A1 = *(const h8*)(a1 + 32 * (kb - PF + i));
      h8 bb0 = B0[i], bb1 = B1[i];
      B0[i] = *(const h8*)(b0 + 32 * (kb + i));
      B1[i] = *(const h8*)(b1 + 32 * (kb + i));
      acc00 = __builtin_amdgcn_mfma_f32_16x16x32_f16(A0, bb0, acc00, 0, 0, 0);
      acc01 = __builtin_amdgcn_mfma_f32_16x16x32_f16(A0, bb1, acc01, 0, 0, 0);
      acc10 = __builtin_amdgcn_mfma_f32_16x16x32_f16(A1, bb0, acc10, 0, 0, 0);
      acc11 = __builtin_amdgcn_mfma_f32_16x16x32_f16(A1, bb1, acc11, 0, 0, 0);
    }
  }
#pragma unroll
  for (int i = 0; i < PF; i++) {
    h8 A0 = *(const h8*)(a0 + 32 * (16 - PF + i));
    h8 A1 = *(const h8*)(a1 + 32 * (16 - PF + i));
    acc00 = __builtin_amdgcn_mfma_f32_16x16x32_f16(A0, B0[i], acc00, 0, 0, 0);
    acc01 = __builtin_amdgcn_mfma_f32_16x16x32_f16(A0, B1[i], acc01, 0, 0, 0);
    acc10 = __builtin_amdgcn_mfma_f32_16x16x32_f16(A1, B0[i], acc10, 0, 0, 0);
    acc11 = __builtin_amdgcn_mfma_f32_16x16x32_f16(A1, B1[i], acc11, 0, 0, 0);
  }
  for (int ni = 0; ni < 2; ni++) {
    int v = n0 + ni * 16 + l15;
    float bias = fcb[v];
    f4 am0 = ni ? acc01 : acc00;
    f4 am1 = ni ? acc11 : acc10;
    for (int i = 0; i < 4; i++) {
      int br0 = q * 4 + i;
      out[((size_t)br0 * TSEQ + tstep) * VOC + v] = am0[i] + bias;
      out[((size_t)(br0 + 16) * TSEQ + tstep) * VOC + v] = am1[i] + bias;
    }
  }
}

// ---- alpha-phase attention for one batch row per block ----
// escore batches 4 tt rows (16 loads in flight, reduces deferred);
// wsum processes both col-groups jointly with tt-unroll 8 (32 loads in
// flight). Accumulation ORDER per output is unchanged vs the verified
// round-3 kernel -> bit-identical results.
__device__ void attention_alpha(int t, const float* sWaF, const float* UaEnc,
                                const _Float16* eWM, const float* va,
                                float* gxC, float* moC, float* out,
                                float* sW, float* sva, float* sAl) {
  const int b = blockIdx.x;
  const int tid = threadIdx.x;
  for (int i = tid; i < HID / 4; i += NTHR) {
    *(f4*)(sW + 4 * i) = *(const f4*)(sWaF + (size_t)b * HID + 4 * i);
    *(f4*)(sva + 4 * i) = *(const f4*)(va + 4 * i);
  }
  __syncthreads();
  const int wid = tid >> 6, lane = tid & 63;
  // escore: wave wid owns tt in [wid*16, wid*16+16), 4 rows per batch
  for (int t0 = wid * 16; t0 < wid * 16 + 16; t0 += 4) {
    const float* ue = UaEnc + (size_t)(b * TSEQ + t0) * HID;
    float a0 = 0.f, a1 = 0.f, a2 = 0.f, a3 = 0.f;
#pragma unroll
    for (int j = 0; j < 4; j++) {
      int h = (j * 64 + lane) * 4;
      f4 w = *(const f4*)(sW + h);
      f4 vv = *(const f4*)(sva + h);
      f4 u0 = *(const f4*)(ue + h);
      f4 u1 = *(const f4*)(ue + HID + h);
      f4 u2 = *(const f4*)(ue + 2 * HID + h);
      f4 u3 = *(const f4*)(ue + 3 * HID + h);
#pragma unroll
      for (int e = 0; e < 4; e++) {
        a0 += vv[e] * fast_tanh(w[e] + u0[e]);
        a1 += vv[e] * fast_tanh(w[e] + u1[e]);
        a2 += vv[e] * fast_tanh(w[e] + u2[e]);
        a3 += vv[e] * fast_tanh(w[e] + u3[e]);
      }
    }
    for (int off = 32; off; off >>= 1) {
      a0 += __shfl_xor(a0, off, 64);
      a1 += __shfl_xor(a1, off, 64);
      a2 += __shfl_xor(a2, off, 64);
      a3 += __shfl_xor(a3, off, 64);
    }
    if (lane == 0) {
      sAl[t0] = a0; sAl[t0 + 1] = a1; sAl[t0 + 2] = a2; sAl[t0 + 3] = a3;
    }
  }
  __syncthreads();
  if (wid == 0) {
    float e = sAl[lane];
    float mx = e;
    for (int off = 32; off; off >>= 1) mx = fmaxf(mx, __shfl_xor(mx, off, 64));
    float p = __expf(e - mx);
    float s = p;
    for (int off = 32; off; off >>= 1) s += __shfl_xor(s, off, 64);
    float al = p / s;
    sAl[lane] = al;
    out[ALPHA_OFF + ((size_t)b * TSEQ + t) * TSEQ + lane] = al;
  }
  __syncthreads();
  // wsum: thread owns cols [tid*8, +8) and [tid*8+2048, +8)
  {
    const int c0 = tid * 8;
    const int c1 = c0 + 2048;
    const _Float16* e0 = eWM + (size_t)b * TSEQ * 4096 + c0;
    const _Float16* e1 = e0 + 2048;
    f4 A0 = {0.f, 0.f, 0.f, 0.f}, B0v = {0.f, 0.f, 0.f, 0.f};
    f4 A1 = {0.f, 0.f, 0.f, 0.f}, B1v = {0.f, 0.f, 0.f, 0.f};
    for (int tt = 0; tt < TSEQ; tt += 8) {
      h8 v0[8], v1[8];
#pragma unroll
      for (int r = 0; r < 8; r++) {
        v0[r] = *(const h8*)(e0 + (size_t)(tt + r) * 4096);
        v1[r] = *(const h8*)(e1 + (size_t)(tt + r) * 4096);
      }
#pragma unroll
      for (int r = 0; r < 8; r++) {
        float al = sAl[tt + r];
        A0[0] += al * (float)v0[r][0]; A0[1] += al * (float)v0[r][1];
        A0[2] += al * (float)v0[r][2]; A0[3] += al * (float)v0[r][3];
        B0v[0] += al * (float)v0[r][4]; B0v[1] += al * (float)v0[r][5];
        B0v[2] += al * (float)v0[r][6]; B0v[3] += al * (float)v0[r][7];
        A1[0] += al * (float)v1[r][0]; A1[1] += al * (float)v1[r][1];
        A1[2] += al * (float)v1[r][2]; A1[3] += al * (float)v1[r][3];
        B1v[0] += al * (float)v1[r][4]; B1v[1] += al * (float)v1[r][5];
        B1v[2] += al * (float)v1[r][6]; B1v[3] += al * (float)v1[r][7];
      }
    }
    float* dst0 = gxC + (size_t)b * G3 + c0;           // c0 < 2048 < G3 always
    *(f4*)dst0 = A0;
    *(f4*)(dst0 + 4) = B0v;
    float* dst1 = (c1 < G3) ? (gxC + (size_t)b * G3 + c1)
                            : (moC + (size_t)b * HID + (c1 - G3));
    *(f4*)dst1 = A1;
    *(f4*)(dst1 + 4) = B1v;
  }
}

__global__ __launch_bounds__(NTHR, 2) void dec_kernel(
    const float* enc, const float* hid, const float* Wsw, const float* Wsb,
    const float* embw, const float* embb, const float* wih, const float* whh,
    const float* bih, const float* bhh, const float* Wa, const float* Ua,
    const float* va, const float* mow, const float* mob, const float* fcw,
    const float* fcb, float* out, unsigned char* ws) {
  __shared__ float sW[HID];
  __shared__ float sva[HID];
  __shared__ float sAl[TSEQ];

  unsigned* ws_u = (unsigned*)ws;
  _Float16* WaF  = (_Float16*)(ws + BAR_BYTES);
  _Float16* WhhF = WaF + S_Wa;
  _Float16* WihF = WhhF + S_Whh;
  _Float16* embT = WihF + S_Wih;
  _Float16* UaF  = embT + S_embT;
  _Float16* moF  = UaF + S_Ua;
  _Float16* fcF  = moF + S_mo;
  _Float16* encF = fcF + S_fc;
  _Float16* W1F  = encF + S_enc;
  _Float16* W2F  = W1F + S_W1;
  _Float16* eWM  = W2F + S_W2;
  _Float16* si16 = eWM + S_eWM;
  _Float16* yi16 = si16 + (size_t)BSZ * HID;
  _Float16* m16  = yi16 + (size_t)BSZ * HID;
  float* UaEnc  = (float*)(m16 + (size_t)BSZ * MOU);
  float* gxC    = UaEnc + (size_t)BSZ * TSEQ * HID;
  float* gxY    = gxC + (size_t)BSZ * G3;
  float* ghF    = gxY + (size_t)BSZ * G3;
  float* moC    = ghF + (size_t)BSZ * G3;
  float* moY    = moC + (size_t)BSZ * HID;
  float* siF    = moY + (size_t)BSZ * HID;
  float* sWaF   = siF + (size_t)BSZ * HID;
  float* biasGx = sWaF + (size_t)BSZ * HID;
  float* biasMo = biasGx + G3;

  const int tid = threadIdx.x;
  const int nb  = gridDim.x;
  const int gid = blockIdx.x * NTHR + tid;
  const int gsz = nb * NTHR;
  const int lane = tid & 63;
  const int wid = tid >> 6;
  const int gw = (blockIdx.x << 2) + wid;
  const int nwv = nb << 2;
  unsigned g = 0;

  // ---- phase 0: casts + si0 + embT + bias folds ----
  cast16v(Wa, WaF, S_Wa, gid, gsz);
  cast16v(whh, WhhF, S_Whh, gid, gsz);
  cast16v(wih, WihF, S_Wih, gid, gsz);
  cast16v(Ua, UaF, S_Ua, gid, gsz);
  cast16v(mow, moF, S_mo, gid, gsz);
  cast16v(fcw, fcF, S_fc, gid, gsz);
  cast16v(enc, encF, S_enc, gid, gsz);
  // embT[h][e] = emb_w[e][h]
  for (int i = gid; i < EMB * HID; i += gsz) {
    int e = i >> 10, h = i & (HID - 1);
    embT[(size_t)h * EMB + e] = (_Float16)embw[i];
  }
  for (int i = gid; i < BSZ * HID; i += gsz) yi16[i] = (_Float16)0.f;
  // si0
  for (int o = gw; o < BSZ * HID; o += nwv) {
    int b = o >> 10, h = o & (HID - 1);
    const float* hv = hid + ((size_t)BSZ + b) * HID;  // hidden_enc[1]
    const float* wr = Wsw + (size_t)h * HID;
    float a = 0.f;
    for (int k = lane; k < HID; k += 64) a += hv[k] * wr[k];
    for (int off = 32; off; off >>= 1) a += __shfl_xor(a, off, 64);
    if (lane == 0) {
      float v = fast_tanh(a + Wsb[h]);
      siF[o] = v;
      si16[o] = (_Float16)v;
    }
  }
  // biasGx[n] = Wih_ye[n,:]@emb_b + bih[n] ; biasMo[n] = mo_ye[n,:]@emb_b + mob[n]
  for (int o = gw; o < G3 + HID; o += nwv) {
    const float* wr;
    if (o < G3) wr = wih + (size_t)o * KX;                      // cols [0,512)
    else        wr = mow + (size_t)(o - G3) * KMO + 3 * HID;    // cols [3072,3584)
    float a = 0.f;
    for (int k = lane; k < EMB; k += 64) a += wr[k] * embb[k];
    for (int off = 32; off; off >>= 1) a += __shfl_xor(a, off, 64);
    if (lane == 0) {
      if (o < G3) biasGx[o] = a + bih[o];
      else        biasMo[o - G3] = a + mob[o - G3];
    }
  }
  gbar(ws_u, g++);

  // ---- pre1: UaEnc, eWM, W1, W2, sWa(0) ----
  {
    const int q = lane >> 4, c = lane & 15;
    for (int tile = gw; tile < 57472; tile += nwv) {
      if (tile < 8192) {                       // UaEnc = enc@Ua^T (f32)
        int tm = tile & 127, tn = tile >> 7;
        int r0 = tm << 4, n0 = tn << 4;
        f4 acc = {0.f, 0.f, 0.f, 0.f};
        acc = gemm16p<8>(encF + (size_t)r0 * (2 * HID), 2 * HID,
                         UaF + (size_t)n0 * (2 * HID), 2 * HID, 2 * HID, acc);
        int col = n0 + c;
        for (int i = 0; i < 4; i++)
          UaEnc[(size_t)(r0 + q * 4 + i) * HID + col] = acc[i];
      } else if (tile < 40960) {               // eWM = [enc@Wih_ctx^T | enc@mo_ctx^T]
        int idx = tile - 8192;
        int r0 = (idx >> 8) << 4, n0 = (idx & 255) << 4;
        const _Float16* Bp; int ldb;
        if (n0 < G3) { Bp = WihF + (size_t)n0 * KX + EMB; ldb = KX; }
        else         { Bp = moF + (size_t)(n0 - G3) * KMO + HID; ldb = KMO; }
        f4 acc = {0.f, 0.f, 0.f, 0.f};
        acc = gemm16p<8>(encF + (size_t)r0 * (2 * HID), 2 * HID, Bp, ldb, 2 * HID, acc);
        int col = n0 + c;
        for (int i = 0; i < 4; i++)
          eWM[(size_t)(r0 + q * 4 + i) * 4096 + col] = (_Float16)acc[i];
      } else if (tile < 53248) {               // W1[n,h] = Wih_ye[n,:]@embT[h,:]
        int idx = tile - 40960;
        int n0 = (idx >> 6) << 4, h0 = (idx & 63) << 4;
        f4 acc = {0.f, 0.f, 0.f, 0.f};
        acc = gemm16p<8>(WihF + (size_t)n0 * KX, KX, embT + (size_t)h0 * EMB, EMB, EMB, acc);
        int col = h0 + c;
        for (int i = 0; i < 4; i++)
          W1F[(size_t)(n0 + q * 4 + i) * HID + col] = (_Float16)acc[i];
      } else if (tile < 57344) {               // W2[n,h] = mo_ye[n,:]@embT[h,:]
        int idx = tile - 53248;
        int n0 = (idx >> 6) << 4, h0 = (idx & 63) << 4;
        f4 acc = {0.f, 0.f, 0.f, 0.f};
        acc = gemm16p<8>(moF + (size_t)n0 * KMO + 3 * HID, KMO,
                         embT + (size_t)h0 * EMB, EMB, EMB, acc);
        int col = h0 + c;
        for (int i = 0; i < 4; i++)
          W2F[(size_t)(n0 + q * 4 + i) * HID + col] = (_Float16)acc[i];
      } else {                                 // sWa(0) = si0@Wa^T
        int idx = tile - 57344;
        int n0 = (idx >> 1) << 4, m0 = (idx & 1) << 4;
        f4 acc = {0.f, 0.f, 0.f, 0.f};
        acc = gemm16p<8>(si16 + (size_t)m0 * HID, HID, WaF + (size_t)n0 * HID, HID, HID, acc);
        int col = n0 + c;
        for (int i = 0; i < 4; i++)
          sWaF[(size_t)(m0 + q * 4 + i) * HID + col] = acc[i];
      }
    }
  }
  gbar(ws_u, g++);

  // ---- time loop: 3 phases/step ----
  for (int t = 0; t < TSEQ; t++) {
    // alpha: attention(t) on blocks 0..31 ; gh/gxY/moY tiles + fc(t-1) elsewhere
    if (blockIdx.x < BSZ) {
      attention_alpha(t, sWaF, UaEnc, eWM, va, gxC, moC, out, sW, sva, sAl);
    } else {
      const _Float16* yiPtr = (t == 0) ? yi16 : si16;
      int units = (t > 0) ? 1896 : 896;
      for (int u = gw - 128; u < units; u += nwv - 128) {
        if (u < 896)
          alpha_tile(u, yiPtr, si16, WhhF, W1F, W2F, bhh, biasGx, biasMo, ghF, gxY, moY);
        else
          fc_tile(u - 896, m16, fcF, fcb, out, t - 1);
      }
    }
    gbar(ws_u, g++);
    // beta: GRU -> si_new
    if (gid < BSZ * (HID / 4)) {
      int b = gid >> 8, h4 = (gid & 255) * 4;
      const float* gc = gxC + (size_t)b * G3;
      const float* gy = gxY + (size_t)b * G3;
      const float* gh = ghF + (size_t)b * G3;
      f4 gr = *(const f4*)(gc + h4) + *(const f4*)(gy + h4);
      f4 hr = *(const f4*)(gh + h4);
      f4 gz = *(const f4*)(gc + HID + h4) + *(const f4*)(gy + HID + h4);
      f4 hz = *(const f4*)(gh + HID + h4);
      f4 gn = *(const f4*)(gc + 2 * HID + h4) + *(const f4*)(gy + 2 * HID + h4);
      f4 hn = *(const f4*)(gh + 2 * HID + h4);
      f4 s  = *(const f4*)(siF + (size_t)b * HID + h4);
      f4 sn;
      h4v sh;
      for (int j = 0; j < 4; j++) {
        float r = fast_sig(gr[j] + hr[j]);
        float z = fast_sig(gz[j] + hz[j]);
        float n = fast_tanh(gn[j] + r * hn[j]);
        sn[j] = (1.f - z) * n + z * s[j];
        sh[j] = (_Float16)sn[j];
      }
      *(f4*)(siF + (size_t)b * HID + h4) = sn;
      *(h4v*)(si16 + (size_t)b * HID + h4) = sh;
    }
    gbar(ws_u, g++);
    // gamma: mo_si+maxout -> m16 ; sWa(t+1)
    {
      int lim = (t + 1 < TSEQ) ? 256 : 128;
      for (int tile = gw; tile < lim; tile += nwv)
        gamma_tile(tile, si16, moF, WaF, moC, moY, sWaF, m16);
    }
    gbar(ws_u, g++);
  }
  // tail: fc for t = 63 over all waves
  for (int tile = gw; tile < FC_TILES; tile += nwv)
    fc_tile(tile, m16, fcF, fcb, out, TSEQ - 1);
}

extern "C" void kernel_launch(void* const* d_in, const int* in_sizes, int n_in,
                              void* d_out, int out_size, void* d_ws, size_t ws_size,
                              hipStream_t stream) {
  (void)in_sizes; (void)n_in; (void)out_size; (void)ws_size;
  hipMemsetAsync(d_ws, 0, BAR_BYTES, stream);  // barrier flags/release
  const float* enc = (const float*)d_in[0];
  const float* hid = (const float*)d_in[1];
  const float* Wsw = (const float*)d_in[2];
  const float* Wsb = (const float*)d_in[3];
  const float* embw = (const float*)d_in[4];
  const float* embb = (const float*)d_in[5];
  const float* wih = (const float*)d_in[6];
  const float* whh = (const float*)d_in[7];
  const float* bih = (const float*)d_in[8];
  const float* bhh = (const float*)d_in[9];
  const float* Wa = (const float*)d_in[10];
  const float* Ua = (const float*)d_in[11];
  const float* va = (const float*)d_in[12];
  const float* mow = (const float*)d_in[13];
  const float* mob = (const float*)d_in[14];
  const float* fcw = (const float*)d_in[15];
  const float* fcb = (const float*)d_in[16];
  float* out = (float*)d_out;
  unsigned char* ws = (unsigned char*)d_ws;
  void* args[] = {&enc, &hid, &Wsw, &Wsb, &embw, &embb, &wih, &whh, &bih, &bhh,
                  &Wa, &Ua, &va, &mow, &mob, &fcw, &fcb, &out, &ws};
  int occ = 1;
  if (hipOccupancyMaxActiveBlocksPerMultiprocessor(&occ, dec_kernel, NTHR, 0) != hipSuccess || occ < 1)
    occ = 1;
  int grid = (occ >= 2) ? NBLK : 256;
  hipLaunchCooperativeKernel((void*)dec_kernel, dim3(grid), dim3(NTHR),
                             (void**)args, 0, stream);
}

// Round 7
// 4985.644 us; speedup vs baseline: 1.6264x; 1.2017x over previous
//
#include <hip/hip_runtime.h>
#include <hip/hip_fp16.h>

#define NBLK 512
#define NTHR 256

constexpr int BSZ = 32;
constexpr int TSEQ = 64;
constexpr int HID = 1024;
constexpr int EMB = 512;
constexpr int MOU = 512;     // M
constexpr int VOC = 32000;
constexpr int KX  = 2560;    // 2H + E (wih leading dim)
constexpr int KMO = 3584;    // 3H + E (mo_w leading dim)
constexpr int G3  = 3072;    // 3H
constexpr int FC_TILES = VOC / 32;   // 1000
constexpr size_t ALPHA_OFF = (size_t)BSZ * TSEQ * VOC;
// barrier region: 8 release copies 4KB apart (32KB) + 512 flag lines (32KB)
constexpr size_t BAR_BYTES = 65536;

constexpr size_t S_Wa   = (size_t)HID * HID;            // 1M
constexpr size_t S_Whh  = (size_t)G3 * HID;             // 3M
constexpr size_t S_Wih  = (size_t)G3 * KX;              // 7.86M (pre only)
constexpr size_t S_embT = (size_t)HID * EMB;            // 0.5M  (pre only)
constexpr size_t S_Ua   = (size_t)HID * 2 * HID;        // 2M    (pre only)
constexpr size_t S_mo   = (size_t)2 * MOU * KMO;        // 3.67M
constexpr size_t S_fc   = (size_t)VOC * MOU;            // 16.4M
constexpr size_t S_enc  = (size_t)BSZ * TSEQ * 2 * HID; // 4.19M (pre only)
constexpr size_t S_W1   = (size_t)G3 * HID;             // 3.1M
constexpr size_t S_W2   = (size_t)HID * HID;            // 1M
constexpr size_t S_eWM  = (size_t)BSZ * TSEQ * 4096;    // 8.39M (encW|encMo)

typedef _Float16 h8 __attribute__((ext_vector_type(8)));
typedef _Float16 h4v __attribute__((ext_vector_type(4)));
typedef float f4 __attribute__((ext_vector_type(4)));

__device__ inline float fast_tanh(float x) {
  float e = __expf(2.f * x);
  return (e - 1.f) / (e + 1.f);
}
__device__ inline float fast_sig(float x) { return 1.f / (1.f + __expf(-x)); }

// ---- distributed flag barrier, multi-line release ----
// fence=false: caller's writes are not read on-device before the next
// full-fence barrier (fc logits). __syncthreads drains vmcnt for all waves,
// so loads/stores reached L2; only the cross-XCD writeback is skipped.
__device__ inline void gbar(unsigned* ws_u, unsigned g, bool fence) {
  unsigned* flags = ws_u + 8192;
  __syncthreads();
  if (blockIdx.x == 0) {
    if (threadIdx.x < 64) {
      const int lane = threadIdx.x;
      const int nb = gridDim.x;
      for (;;) {
        bool ok = true;
        for (int i = lane; i < nb; i += 64)
          if (i != 0)
            ok &= (__hip_atomic_load(flags + (size_t)i * 16, __ATOMIC_RELAXED,
                                     __HIP_MEMORY_SCOPE_AGENT) > g);
        if (__builtin_amdgcn_ballot_w64(ok) == ~0ull) break;
        __builtin_amdgcn_s_sleep(2);
      }
      __threadfence();
      if (lane < 8)
        __hip_atomic_store(ws_u + (size_t)lane * 1024, g + 1, __ATOMIC_RELAXED,
                           __HIP_MEMORY_SCOPE_AGENT);
    }
    __syncthreads();
  } else {
    if (threadIdx.x == 0) {
      if (fence) __threadfence();
      __hip_atomic_store(flags + (size_t)blockIdx.x * 16, g + 1, __ATOMIC_RELAXED,
                         __HIP_MEMORY_SCOPE_AGENT);
      unsigned* myrel = ws_u + (size_t)(blockIdx.x & 7) * 1024;
      while (__hip_atomic_load(myrel, __ATOMIC_RELAXED, __HIP_MEMORY_SCOPE_AGENT) <= g)
        __builtin_amdgcn_s_sleep(2);
      __threadfence();
    }
    __syncthreads();
  }
}

// ---- pipelined 16x16 tile GEMM: C += A[16,klen] * W[16,klen]^T ----
template <int PF>
__device__ inline f4 gemm16p(const _Float16* A, int lda, const _Float16* W, int ldw,
                             int klen, f4 accin) {
  const int lane = threadIdx.x & 63;
  const _Float16* ap = A + (size_t)(lane & 15) * lda + ((lane >> 4) << 3);
  const _Float16* wp = W + (size_t)(lane & 15) * ldw + ((lane >> 4) << 3);
  const int nk = klen >> 5;
  f4 acc[4];
  acc[0] = accin;
  acc[1] = f4{0.f, 0.f, 0.f, 0.f};
  acc[2] = f4{0.f, 0.f, 0.f, 0.f};
  acc[3] = f4{0.f, 0.f, 0.f, 0.f};
  h8 ab[PF], wb[PF];
#pragma unroll
  for (int i = 0; i < PF; i++) {
    ab[i] = *(const h8*)(ap + 32 * i);
    wb[i] = *(const h8*)(wp + 32 * i);
  }
  for (int kb = PF; kb < nk; kb += PF) {
#pragma unroll
    for (int i = 0; i < PF; i++) {
      h8 a = ab[i], w = wb[i];
      ab[i] = *(const h8*)(ap + 32 * (kb + i));
      wb[i] = *(const h8*)(wp + 32 * (kb + i));
      acc[i & 3] = __builtin_amdgcn_mfma_f32_16x16x32_f16(a, w, acc[i & 3], 0, 0, 0);
    }
  }
#pragma unroll
  for (int i = 0; i < PF; i++)
    acc[i & 3] = __builtin_amdgcn_mfma_f32_16x16x32_f16(ab[i], wb[i], acc[i & 3], 0, 0, 0);
  return (acc[0] + acc[1]) + (acc[2] + acc[3]);
}

__device__ inline void cast16v(const float* s, _Float16* d, size_t n, int gid, int gsz) {
  const float4* s4 = (const float4*)s;
  size_t n4 = n >> 2;
  for (size_t i = (size_t)gid; i < n4; i += (size_t)gsz) {
    float4 v = s4[i];
    h4v o = {(_Float16)v.x, (_Float16)v.y, (_Float16)v.z, (_Float16)v.w};
    *(h4v*)(d + 4 * i) = o;
  }
}

// ---- gamma tile: all si(t)-dependent GEMMs.
// [0,128) mo_si+maxout -> m16 ; [128,256) sWa(t+1) ; [256,640) gh(t+1) ;
// [640,1024) gxY(t+1) ; [1024,1152) moY(t+1) (into moYw; mo_si reads moYr).
__device__ void gamma_tile2(int tile, const _Float16* si16, const _Float16* moF,
                            const _Float16* WaF, const _Float16* WhhF,
                            const _Float16* W1F, const _Float16* W2F,
                            const float* moC, const float* moYr, float* moYw,
                            const float* bhh, const float* biasGx, const float* biasMo,
                            float* sWaF, float* ghF, float* gxY, _Float16* m16) {
  const int lane = threadIdx.x & 63;
  const int q = lane >> 4, c = lane & 15;
  if (tile < 128) {
    int n0 = (tile >> 1) << 4, m0 = (tile & 1) << 4;
    int col = n0 + c;
    f4 acc;
    for (int i = 0; i < 4; i++) {
      size_t r = (size_t)(m0 + q * 4 + i) * HID + col;
      acc[i] = moC[r] + moYr[r];
    }
    acc = gemm16p<16>(si16 + (size_t)m0 * HID, HID, moF + (size_t)n0 * KMO, KMO, HID, acc);
    for (int i = 0; i < 4; i++) {
      float v = acc[i];
      float o = __shfl_xor(v, 1, 64);
      if ((lane & 1) == 0) {
        int row = m0 + q * 4 + i;
        m16[(size_t)row * MOU + (col >> 1)] = (_Float16)fmaxf(v, o);
      }
    }
  } else if (tile < 256) {
    int idx = tile - 128;
    int n0 = (idx >> 1) << 4, m0 = (idx & 1) << 4;
    f4 acc = {0.f, 0.f, 0.f, 0.f};
    acc = gemm16p<16>(si16 + (size_t)m0 * HID, HID, WaF + (size_t)n0 * HID, HID, HID, acc);
    int col = n0 + c;
    for (int i = 0; i < 4; i++) sWaF[(size_t)(m0 + q * 4 + i) * HID + col] = acc[i];
  } else if (tile < 640) {
    int idx = tile - 256;
    int n0 = (idx >> 1) << 4, m0 = (idx & 1) << 4;
    f4 acc = {0.f, 0.f, 0.f, 0.f};
    acc = gemm16p<16>(si16 + (size_t)m0 * HID, HID, WhhF + (size_t)n0 * HID, HID, HID, acc);
    int col = n0 + c; float bb = bhh[col];
    for (int i = 0; i < 4; i++) ghF[(size_t)(m0 + q * 4 + i) * G3 + col] = acc[i] + bb;
  } else if (tile < 1024) {
    int idx = tile - 640;
    int n0 = (idx >> 1) << 4, m0 = (idx & 1) << 4;
    f4 acc = {0.f, 0.f, 0.f, 0.f};
    acc = gemm16p<16>(si16 + (size_t)m0 * HID, HID, W1F + (size_t)n0 * HID, HID, HID, acc);
    int col = n0 + c; float bb = biasGx[col];
    for (int i = 0; i < 4; i++) gxY[(size_t)(m0 + q * 4 + i) * G3 + col] = acc[i] + bb;
  } else {
    int idx = tile - 1024;
    int n0 = (idx >> 1) << 4, m0 = (idx & 1) << 4;
    f4 acc = {0.f, 0.f, 0.f, 0.f};
    acc = gemm16p<16>(si16 + (size_t)m0 * HID, HID, W2F + (size_t)n0 * HID, HID, HID, acc);
    int col = n0 + c; float bb = biasMo[col];
    for (int i = 0; i < 4; i++) moYw[(size_t)(m0 + q * 4 + i) * HID + col] = acc[i] + bb;
  }
}

// ---- one fc tile (32 vocab cols): logits[:, tstep, n0:n0+32], nt stores ----
__device__ void fc_tile(int tile, const _Float16* m16g, const _Float16* fcF,
                        const float* fcb, float* out, int tstep) {
  const int lane = threadIdx.x & 63;
  const int q = lane >> 4, l15 = lane & 15;
  const _Float16* a0 = m16g + (size_t)l15 * MOU + (q << 3);
  const _Float16* a1 = a0 + (size_t)16 * MOU;
  int n0 = tile * 32;
  const _Float16* b0 = fcF + (size_t)(n0 + l15) * MOU + (q << 3);
  const _Float16* b1 = b0 + (size_t)16 * MOU;
  f4 z = {0.f, 0.f, 0.f, 0.f};
  f4 acc00 = z, acc01 = z, acc10 = z, acc11 = z;
  constexpr int PF = 4;
  h8 B0[PF], B1[PF];
#pragma unroll
  for (int i = 0; i < PF; i++) {
    B0[i] = *(const h8*)(b0 + 32 * i);
    B1[i] = *(const h8*)(b1 + 32 * i);
  }
  for (int kb = PF; kb < 16; kb += PF) {
#pragma unroll
    for (int i = 0; i < PF; i++) {
      h8 A0 = *(const h8*)(a0 + 32 * (kb - PF + i));
      h8 A1 = *(const h8*)(a1 + 32 * (kb - PF + i));
      h8 bb0 = B0[i], bb1 = B1[i];
      B0[i] = *(const h8*)(b0 + 32 * (kb + i));
      B1[i] = *(const h8*)(b1 + 32 * (kb + i));
      acc00 = __builtin_amdgcn_mfma_f32_16x16x32_f16(A0, bb0, acc00, 0, 0, 0);
      acc01 = __builtin_amdgcn_mfma_f32_16x16x32_f16(A0, bb1, acc01, 0, 0, 0);
      acc10 = __builtin_amdgcn_mfma_f32_16x16x32_f16(A1, bb0, acc10, 0, 0, 0);
      acc11 = __builtin_amdgcn_mfma_f32_16x16x32_f16(A1, bb1, acc11, 0, 0, 0);
    }
  }
#pragma unroll
  for (int i = 0; i < PF; i++) {
    h8 A0 = *(const h8*)(a0 + 32 * (16 - PF + i));
    h8 A1 = *(const h8*)(a1 + 32 * (16 - PF + i));
    acc00 = __builtin_amdgcn_mfma_f32_16x16x32_f16(A0, B0[i], acc00, 0, 0, 0);
    acc01 = __builtin_amdgcn_mfma_f32_16x16x32_f16(A0, B1[i], acc01, 0, 0, 0);
    acc10 = __builtin_amdgcn_mfma_f32_16x16x32_f16(A1, B0[i], acc10, 0, 0, 0);
    acc11 = __builtin_amdgcn_mfma_f32_16x16x32_f16(A1, B1[i], acc11, 0, 0, 0);
  }
  for (int ni = 0; ni < 2; ni++) {
    int v = n0 + ni * 16 + l15;
    float bias = fcb[v];
    f4 am0 = ni ? acc01 : acc00;
    f4 am1 = ni ? acc11 : acc10;
    for (int i = 0; i < 4; i++) {
      int br0 = q * 4 + i;
      __builtin_nontemporal_store(am0[i] + bias,
          &out[((size_t)br0 * TSEQ + tstep) * VOC + v]);
      __builtin_nontemporal_store(am1[i] + bias,
          &out[((size_t)(br0 + 16) * TSEQ + tstep) * VOC + v]);
    }
  }
}

// ---- alpha-phase: attention + fused GRU for one batch row per block ----
// escore/softmax/wsum identical math to the verified round-6 kernel; gxC goes
// to LDS (only the GRU reads it), moC to global. Then the GRU for batch b runs
// here (gxY/ghF from gamma(t-1)), producing si(t) in siF/si16.
__device__ void attention_gru(int t, const float* sWaF, const float* UaEnc,
                              const _Float16* eWM, const float* va,
                              const float* gxY, const float* ghF,
                              float* moC, float* siF, _Float16* si16, float* out,
                              float* sW, float* sva, float* sAl, float* sgxC) {
  const int b = blockIdx.x;
  const int tid = threadIdx.x;
  for (int i = tid; i < HID / 4; i += NTHR) {
    *(f4*)(sW + 4 * i) = *(const f4*)(sWaF + (size_t)b * HID + 4 * i);
    *(f4*)(sva + 4 * i) = *(const f4*)(va + 4 * i);
  }
  __syncthreads();
  const int wid = tid >> 6, lane = tid & 63;
  // escore: wave wid owns tt in [wid*16, wid*16+16), 4 rows per batch
  for (int t0 = wid * 16; t0 < wid * 16 + 16; t0 += 4) {
    const float* ue = UaEnc + (size_t)(b * TSEQ + t0) * HID;
    float a0 = 0.f, a1 = 0.f, a2 = 0.f, a3 = 0.f;
#pragma unroll
    for (int j = 0; j < 4; j++) {
      int h = (j * 64 + lane) * 4;
      f4 w = *(const f4*)(sW + h);
      f4 vv = *(const f4*)(sva + h);
      f4 u0 = *(const f4*)(ue + h);
      f4 u1 = *(const f4*)(ue + HID + h);
      f4 u2 = *(const f4*)(ue + 2 * HID + h);
      f4 u3 = *(const f4*)(ue + 3 * HID + h);
#pragma unroll
      for (int e = 0; e < 4; e++) {
        a0 += vv[e] * fast_tanh(w[e] + u0[e]);
        a1 += vv[e] * fast_tanh(w[e] + u1[e]);
        a2 += vv[e] * fast_tanh(w[e] + u2[e]);
        a3 += vv[e] * fast_tanh(w[e] + u3[e]);
      }
    }
    for (int off = 32; off; off >>= 1) {
      a0 += __shfl_xor(a0, off, 64);
      a1 += __shfl_xor(a1, off, 64);
      a2 += __shfl_xor(a2, off, 64);
      a3 += __shfl_xor(a3, off, 64);
    }
    if (lane == 0) {
      sAl[t0] = a0; sAl[t0 + 1] = a1; sAl[t0 + 2] = a2; sAl[t0 + 3] = a3;
    }
  }
  __syncthreads();
  if (wid == 0) {
    float e = sAl[lane];
    float mx = e;
    for (int off = 32; off; off >>= 1) mx = fmaxf(mx, __shfl_xor(mx, off, 64));
    float p = __expf(e - mx);
    float s = p;
    for (int off = 32; off; off >>= 1) s += __shfl_xor(s, off, 64);
    float al = p / s;
    sAl[lane] = al;
    out[ALPHA_OFF + ((size_t)b * TSEQ + t) * TSEQ + lane] = al;
  }
  __syncthreads();
  // wsum: thread owns cols [tid*8, +8) and [tid*8+2048, +8)
  {
    const int c0 = tid * 8;
    const int c1 = c0 + 2048;
    const _Float16* e0 = eWM + (size_t)b * TSEQ * 4096 + c0;
    const _Float16* e1 = e0 + 2048;
    f4 A0 = {0.f, 0.f, 0.f, 0.f}, B0v = {0.f, 0.f, 0.f, 0.f};
    f4 A1 = {0.f, 0.f, 0.f, 0.f}, B1v = {0.f, 0.f, 0.f, 0.f};
    for (int tt = 0; tt < TSEQ; tt += 8) {
      h8 v0[8], v1[8];
#pragma unroll
      for (int r = 0; r < 8; r++) {
        v0[r] = *(const h8*)(e0 + (size_t)(tt + r) * 4096);
        v1[r] = *(const h8*)(e1 + (size_t)(tt + r) * 4096);
      }
#pragma unroll
      for (int r = 0; r < 8; r++) {
        float al = sAl[tt + r];
        A0[0] += al * (float)v0[r][0]; A0[1] += al * (float)v0[r][1];
        A0[2] += al * (float)v0[r][2]; A0[3] += al * (float)v0[r][3];
        B0v[0] += al * (float)v0[r][4]; B0v[1] += al * (float)v0[r][5];
        B0v[2] += al * (float)v0[r][6]; B0v[3] += al * (float)v0[r][7];
        A1[0] += al * (float)v1[r][0]; A1[1] += al * (float)v1[r][1];
        A1[2] += al * (float)v1[r][2]; A1[3] += al * (float)v1[r][3];
        B1v[0] += al * (float)v1[r][4]; B1v[1] += al * (float)v1[r][5];
        B1v[2] += al * (float)v1[r][6]; B1v[3] += al * (float)v1[r][7];
      }
    }
    *(f4*)(sgxC + c0) = A0;
    *(f4*)(sgxC + c0 + 4) = B0v;
    if (c1 < G3) {
      *(f4*)(sgxC + c1) = A1;
      *(f4*)(sgxC + c1 + 4) = B1v;
    } else {
      float* d = moC + (size_t)b * HID + (c1 - G3);
      *(f4*)d = A1;
      *(f4*)(d + 4) = B1v;
    }
  }
  __syncthreads();
  // GRU for batch b: 4 h-elements per thread
  {
    int h4 = tid * 4;
    const float* gy = gxY + (size_t)b * G3;
    const float* gh = ghF + (size_t)b * G3;
    f4 gr = *(const f4*)(sgxC + h4) + *(const f4*)(gy + h4);
    f4 hr = *(const f4*)(gh + h4);
    f4 gz = *(const f4*)(sgxC + HID + h4) + *(const f4*)(gy + HID + h4);
    f4 hz = *(const f4*)(gh + HID + h4);
    f4 gn = *(const f4*)(sgxC + 2 * HID + h4) + *(const f4*)(gy + 2 * HID + h4);
    f4 hn = *(const f4*)(gh + 2 * HID + h4);
    f4 s  = *(const f4*)(siF + (size_t)b * HID + h4);
    f4 sn;
    h4v sh;
    for (int j = 0; j < 4; j++) {
      float r = fast_sig(gr[j] + hr[j]);
      float z = fast_sig(gz[j] + hz[j]);
      float n = fast_tanh(gn[j] + r * hn[j]);
      sn[j] = (1.f - z) * n + z * s[j];
      sh[j] = (_Float16)sn[j];
    }
    *(f4*)(siF + (size_t)b * HID + h4) = sn;
    *(h4v*)(si16 + (size_t)b * HID + h4) = sh;
  }
}

__global__ __launch_bounds__(NTHR, 2) void dec_kernel(
    const float* enc, const float* hid, const float* Wsw, const float* Wsb,
    const float* embw, const float* embb, const float* wih, const float* whh,
    const float* bih, const float* bhh, const float* Wa, const float* Ua,
    const float* va, const float* mow, const float* mob, const float* fcw,
    const float* fcb, float* out, unsigned char* ws) {
  __shared__ float sW[HID];
  __shared__ float sva[HID];
  __shared__ float sAl[TSEQ];
  __shared__ float sgxC[G3];

  unsigned* ws_u = (unsigned*)ws;
  _Float16* WaF  = (_Float16*)(ws + BAR_BYTES);
  _Float16* WhhF = WaF + S_Wa;
  _Float16* WihF = WhhF + S_Whh;
  _Float16* embT = WihF + S_Wih;
  _Float16* UaF  = embT + S_embT;
  _Float16* moF  = UaF + S_Ua;
  _Float16* fcF  = moF + S_mo;
  _Float16* encF = fcF + S_fc;
  _Float16* W1F  = encF + S_enc;
  _Float16* W2F  = W1F + S_W1;
  _Float16* eWM  = W2F + S_W2;
  _Float16* si16 = eWM + S_eWM;
  _Float16* m16  = si16 + (size_t)BSZ * HID;
  float* UaEnc  = (float*)(m16 + (size_t)BSZ * MOU);
  float* gxY    = UaEnc + (size_t)BSZ * TSEQ * HID;
  float* ghF    = gxY + (size_t)BSZ * G3;
  float* moC    = ghF + (size_t)BSZ * G3;
  float* moYbuf = moC + (size_t)BSZ * HID;          // [2][BSZ*HID]
  float* siF    = moYbuf + (size_t)2 * BSZ * HID;
  float* sWaF   = siF + (size_t)BSZ * HID;
  float* biasGx = sWaF + (size_t)BSZ * HID;
  float* biasMo = biasGx + G3;

  const int tid = threadIdx.x;
  const int nb  = gridDim.x;
  const int gid = blockIdx.x * NTHR + tid;
  const int gsz = nb * NTHR;
  const int lane = tid & 63;
  const int wid = tid >> 6;
  const int gw = (blockIdx.x << 2) + wid;
  const int nwv = nb << 2;
  unsigned g = 0;

  // ---- phase 0: casts + si0 + embT + bias folds ----
  cast16v(Wa, WaF, S_Wa, gid, gsz);
  cast16v(whh, WhhF, S_Whh, gid, gsz);
  cast16v(wih, WihF, S_Wih, gid, gsz);
  cast16v(Ua, UaF, S_Ua, gid, gsz);
  cast16v(mow, moF, S_mo, gid, gsz);
  cast16v(fcw, fcF, S_fc, gid, gsz);
  cast16v(enc, encF, S_enc, gid, gsz);
  // embT[h][e] = emb_w[e][h]
  for (int i = gid; i < EMB * HID; i += gsz) {
    int e = i >> 10, h = i & (HID - 1);
    embT[(size_t)h * EMB + e] = (_Float16)embw[i];
  }
  // si0
  for (int o = gw; o < BSZ * HID; o += nwv) {
    int b = o >> 10, h = o & (HID - 1);
    const float* hv = hid + ((size_t)BSZ + b) * HID;  // hidden_enc[1]
    const float* wr = Wsw + (size_t)h * HID;
    float a = 0.f;
    for (int k = lane; k < HID; k += 64) a += hv[k] * wr[k];
    for (int off = 32; off; off >>= 1) a += __shfl_xor(a, off, 64);
    if (lane == 0) {
      float v = fast_tanh(a + Wsb[h]);
      siF[o] = v;
      si16[o] = (_Float16)v;
    }
  }
  // biasGx[n] = Wih_ye[n,:]@emb_b + bih[n] ; biasMo[n] = mo_ye[n,:]@emb_b + mob[n]
  for (int o = gw; o < G3 + HID; o += nwv) {
    const float* wr;
    if (o < G3) wr = wih + (size_t)o * KX;                      // cols [0,512)
    else        wr = mow + (size_t)(o - G3) * KMO + 3 * HID;    // cols [3072,3584)
    float a = 0.f;
    for (int k = lane; k < EMB; k += 64) a += wr[k] * embb[k];
    for (int off = 32; off; off >>= 1) a += __shfl_xor(a, off, 64);
    if (lane == 0) {
      if (o < G3) biasGx[o] = a + bih[o];
      else        biasMo[o - G3] = a + mob[o - G3];
    }
  }
  gbar(ws_u, g++, true);

  // ---- pre1: UaEnc, eWM, W1, W2, sWa(0), gh(0) + fills gxY(0)/moY(0) ----
  {
    const int q = lane >> 4, c = lane & 15;
    for (int tile = gw; tile < 57856; tile += nwv) {
      if (tile < 8192) {                       // UaEnc = enc@Ua^T (f32)
        int tm = tile & 127, tn = tile >> 7;
        int r0 = tm << 4, n0 = tn << 4;
        f4 acc = {0.f, 0.f, 0.f, 0.f};
        acc = gemm16p<8>(encF + (size_t)r0 * (2 * HID), 2 * HID,
                         UaF + (size_t)n0 * (2 * HID), 2 * HID, 2 * HID, acc);
        int col = n0 + c;
        for (int i = 0; i < 4; i++)
          UaEnc[(size_t)(r0 + q * 4 + i) * HID + col] = acc[i];
      } else if (tile < 40960) {               // eWM = [enc@Wih_ctx^T | enc@mo_ctx^T]
        int idx = tile - 8192;
        int r0 = (idx >> 8) << 4, n0 = (idx & 255) << 4;
        const _Float16* Bp; int ldb;
        if (n0 < G3) { Bp = WihF + (size_t)n0 * KX + EMB; ldb = KX; }
        else         { Bp = moF + (size_t)(n0 - G3) * KMO + HID; ldb = KMO; }
        f4 acc = {0.f, 0.f, 0.f, 0.f};
        acc = gemm16p<8>(encF + (size_t)r0 * (2 * HID), 2 * HID, Bp, ldb, 2 * HID, acc);
        int col = n0 + c;
        for (int i = 0; i < 4; i++)
          eWM[(size_t)(r0 + q * 4 + i) * 4096 + col] = (_Float16)acc[i];
      } else if (tile < 53248) {               // W1[n,h] = Wih_ye[n,:]@embT[h,:]
        int idx = tile - 40960;
        int n0 = (idx >> 6) << 4, h0 = (idx & 63) << 4;
        f4 acc = {0.f, 0.f, 0.f, 0.f};
        acc = gemm16p<8>(WihF + (size_t)n0 * KX, KX, embT + (size_t)h0 * EMB, EMB, EMB, acc);
        int col = h0 + c;
        for (int i = 0; i < 4; i++)
          W1F[(size_t)(n0 + q * 4 + i) * HID + col] = (_Float16)acc[i];
      } else if (tile < 57344) {               // W2[n,h] = mo_ye[n,:]@embT[h,:]
        int idx = tile - 53248;
        int n0 = (idx >> 6) << 4, h0 = (idx & 63) << 4;
        f4 acc = {0.f, 0.f, 0.f, 0.f};
        acc = gemm16p<8>(moF + (size_t)n0 * KMO + 3 * HID, KMO,
                         embT + (size_t)h0 * EMB, EMB, EMB, acc);
        int col = h0 + c;
        for (int i = 0; i < 4; i++)
          W2F[(size_t)(n0 + q * 4 + i) * HID + col] = (_Float16)acc[i];
      } else if (tile < 57472) {               // sWa(0) = si0@Wa^T
        int idx = tile - 57344;
        int n0 = (idx >> 1) << 4, m0 = (idx & 1) << 4;
        f4 acc = {0.f, 0.f, 0.f, 0.f};
        acc = gemm16p<8>(si16 + (size_t)m0 * HID, HID, WaF + (size_t)n0 * HID, HID, HID, acc);
        int col = n0 + c;
        for (int i = 0; i < 4; i++)
          sWaF[(size_t)(m0 + q * 4 + i) * HID + col] = acc[i];
      } else {                                 // gh(0) = si0@Whh^T + bhh
        int idx = tile - 57472;
        int n0 = (idx >> 1) << 4, m0 = (idx & 1) << 4;
        f4 acc = {0.f, 0.f, 0.f, 0.f};
        acc = gemm16p<8>(si16 + (size_t)m0 * HID, HID, WhhF + (size_t)n0 * HID, HID, HID, acc);
        int col = n0 + c; float bb = bhh[col];
        for (int i = 0; i < 4; i++)
          ghF[(size_t)(m0 + q * 4 + i) * G3 + col] = acc[i] + bb;
      }
    }
    // fills: gxY(0) = biasGx (yi0=0), moYbuf[0] = biasMo
    for (int i = gid; i < BSZ * G3; i += gsz) {
      int n = i - (i / G3) * G3;
      gxY[i] = biasGx[n];
    }
    for (int i = gid; i < BSZ * HID; i += gsz)
      moYbuf[i] = biasMo[i & (HID - 1)];
  }
  gbar(ws_u, g++, true);

  // ---- time loop: 2 phases/step ----
  for (int t = 0; t < TSEQ; t++) {
    const float* moYr = moYbuf + (size_t)(t & 1) * BSZ * HID;
    float* moYw = moYbuf + (size_t)((t + 1) & 1) * BSZ * HID;
    // alpha': attention+GRU on blocks 0..31 ; fc(t-1) on the rest
    if (blockIdx.x < BSZ) {
      attention_gru(t, sWaF, UaEnc, eWM, va, gxY, ghF, moC, siF, si16, out,
                    sW, sva, sAl, sgxC);
      gbar(ws_u, g++, true);
    } else {
      if (t > 0) {
        int w = (blockIdx.x - BSZ) * 4 + wid;
        int nw = (nb - BSZ) * 4;
        for (int tile = w; tile < FC_TILES; tile += nw)
          fc_tile(tile, m16, fcF, fcb, out, t - 1);
      }
      gbar(ws_u, g++, false);   // logits not read on-device; skip L2 writeback
    }
    // gamma': all si(t)-dependent GEMMs
    {
      int lim = (t + 1 < TSEQ) ? 1152 : 128;
      for (int tile = gw; tile < lim; tile += nwv)
        gamma_tile2(tile, si16, moF, WaF, WhhF, W1F, W2F, moC, moYr, moYw,
                    bhh, biasGx, biasMo, sWaF, ghF, gxY, m16);
    }
    gbar(ws_u, g++, true);
  }
  // tail: fc for t = 63 over all waves
  for (int tile = gw; tile < FC_TILES; tile += nwv)
    fc_tile(tile, m16, fcF, fcb, out, TSEQ - 1);
}

extern "C" void kernel_launch(void* const* d_in, const int* in_sizes, int n_in,
                              void* d_out, int out_size, void* d_ws, size_t ws_size,
                              hipStream_t stream) {
  (void)in_sizes; (void)n_in; (void)out_size; (void)ws_size;
  hipMemsetAsync(d_ws, 0, BAR_BYTES, stream);  // barrier flags/release
  const float* enc = (const float*)d_in[0];
  const float* hid = (const float*)d_in[1];
  const float* Wsw = (const float*)d_in[2];
  const float* Wsb = (const float*)d_in[3];
  const float* embw = (const float*)d_in[4];
  const float* embb = (const float*)d_in[5];
  const float* wih = (const float*)d_in[6];
  const float* whh = (const float*)d_in[7];
  const float* bih = (const float*)d_in[8];
  const float* bhh = (const float*)d_in[9];
  const float* Wa = (const float*)d_in[10];
  const float* Ua = (const float*)d_in[11];
  const float* va = (const float*)d_in[12];
  const float* mow = (const float*)d_in[13];
  const float* mob = (const float*)d_in[14];
  const float* fcw = (const float*)d_in[15];
  const float* fcb = (const float*)d_in[16];
  float* out = (float*)d_out;
  unsigned char* ws = (unsigned char*)d_ws;
  void* args[] = {&enc, &hid, &Wsw, &Wsb, &embw, &embb, &wih, &whh, &bih, &bhh,
                  &Wa, &Ua, &va, &mow, &mob, &fcw, &fcb, &out, &ws};
  int occ = 1;
  if (hipOccupancyMaxActiveBlocksPerMultiprocessor(&occ, dec_kernel, NTHR, 0) != hipSuccess || occ < 1)
    occ = 1;
  int grid = (occ >= 2) ? NBLK : 256;
  hipLaunchCooperativeKernel((void*)dec_kernel, dim3(grid), dim3(NTHR),
                             (void**)args, 0, stream);
}